// Round 6
// baseline (205.356 us; speedup 1.0000x reference)
//
#include <hip/hip_runtime.h>

typedef __attribute__((ext_vector_type(8))) short short8;
typedef __attribute__((ext_vector_type(4))) float f32x4;

constexpr int H = 512, W = 512;
constexpr int P = H * W;     // 262144
constexpr int NSP = 1024;
constexpr int SBLK = 256;    // scatter partial blocks

__device__ inline unsigned short f2bf(float f) {
  unsigned u = __builtin_bit_cast(unsigned, f);
  unsigned r = (u + 0x7fffu + ((u >> 16) & 1u)) >> 16;  // RNE
  return (unsigned short)r;
}

// XCD-band swizzle: 1024 blocks, 8 XCDs round-robin => XCD k owns logical
// ids [k*128,(k+1)*128) = pixel-row band [64k, 64k+64). Producer/consumer
// kernels use the SAME mapping so h2 tiles are read from the writer's L2.
__device__ inline int xcd_swz(int b) { return (b & 7) * 128 + (b >> 3); }

// ---------------- prep: weights -> staged-order bf16 with baked-in swizzle ----------------
// Chunk k (= tap*2+kc) of 16B-cells; cell t = (row r=t>>2, slot'=t&3);
// stored ic-slot s = slot'^(r&3) => linear DMA write + swizzled ds_read conflict-free.
__global__ __launch_bounds__(256) void prep_k(const float* __restrict__ w2,
                                              const float* __restrict__ w3,
                                              unsigned short* __restrict__ wt2s,
                                              unsigned short* __restrict__ wt3s,
                                              unsigned short* __restrict__ zeros) {
  if (blockIdx.x == 0 && threadIdx.x < 128) zeros[threadIdx.x] = 0;  // 256-B zero stub
  int i = blockIdx.x * 256 + threadIdx.x;
  if (i < 36864) {                     // conv2: 18 chunks x 2048 shorts (64 oc rows)
    int k = i >> 11;
    int t = (i >> 3) & 255;
    int e = i & 7;
    int r = t >> 2, sp = t & 3, s = sp ^ (r & 3);
    int tap = k >> 1, ic = (k & 1) * 32 + s * 8 + e;
    wt2s[i] = f2bf(w2[r * 576 + ic * 9 + tap]);
  } else if (i < 46080) {              // conv3: 18 chunks x 512 shorts (16 rows, 10 real)
    int j = i - 36864;
    int k = j >> 9;
    int t = (j >> 3) & 63;
    int e = j & 7;
    int r = t >> 2, sp = t & 3, s = sp ^ (r & 3);
    int tap = k >> 1, ic = (k & 1) * 32 + s * 8 + e;
    wt3s[j] = (r < 10) ? f2bf(w3[r * 576 + ic * 9 + tap]) : (unsigned short)0;
  }
}

// ---------------- conv2f (fused conv1+conv2): raw -> h1(LDS only) -> h2 NHWC bf16 ----------------
// Each block computes conv1 on its 34x10 halo tile straight into the swizzled
// acts layout (no global h1), then runs the MFMA weight-ring pipeline.
__global__ __launch_bounds__(256) void conv2f_k(const float* __restrict__ raw,
                                                const float* __restrict__ w1,
                                                const float* __restrict__ b1,
                                                const unsigned short* __restrict__ wts,
                                                const float* __restrict__ bias,
                                                unsigned short* __restrict__ ynhwc) {
  constexpr int WCS = 2048;                                // weight chunk shorts (4 KiB)
  __shared__ __align__(16) unsigned short acts[344 * 64];  // 44032 B
  __shared__ __align__(16) unsigned short wbuf[3 * WCS];   // 12288 B
  __shared__ float rawt[12 * 36];                          // 1728 B
  int tid = threadIdx.x;
  int lane = tid & 63, wave = tid >> 6;
  int logical = xcd_swz(blockIdx.x);
  int tilex = logical & 15, tiley = logical >> 4;
  int c0 = tilex * 32, r0 = tiley * 8;

  // ---- stage raw halo-of-halo tile [12 rows][36 cols] (rows r0-2..r0+9) ----
  for (int i = tid; i < 432; i += 256) {
    int rr = i / 36, cc = i - rr * 36;
    int gr = r0 + rr - 2, gc = c0 + cc - 2;
    bool ok = ((unsigned)gr < 512u) && ((unsigned)gc < 512u);
    rawt[i] = ok ? raw[gr * 512 + gc] : 0.f;
  }
  // ---- weight prologue chunks 0,1 (land during conv1 compute) ----
#pragma unroll
  for (int k0 = 0; k0 < 2; ++k0) {
    const unsigned short* src = wts + (size_t)k0 * WCS + tid * 8;
    unsigned short* dstb = wbuf + k0 * WCS + wave * 512;
    __builtin_amdgcn_global_load_lds((const __attribute__((address_space(1))) void*)src,
                                     (__attribute__((address_space(3))) void*)dstb, 16, 0, 0);
  }
  __syncthreads();

  // ---- conv1 on the 340-px halo tile, written in swizzled acts layout ----
  char* actw = (char*)acts;
  for (int px = tid; px < 340; px += 256) {
    int prow = px / 34, pcol = px - prow * 34;
    int gr1 = r0 + prow - 1, gc1 = c0 + pcol - 1;
    bool ok1 = ((unsigned)gr1 < 512u) && ((unsigned)gc1 < 512u);
    float in[9];
#pragma unroll
    for (int dy = 0; dy < 3; ++dy)
#pragma unroll
      for (int dx = 0; dx < 3; ++dx)
        in[dy * 3 + dx] = rawt[(prow + dy) * 36 + (pcol + dx)];
#pragma unroll
    for (int s = 0; s < 8; ++s) {
      unsigned u[4];
#pragma unroll
      for (int j = 0; j < 4; ++j) {
        int oc0 = s * 8 + 2 * j;
        float a0 = b1[oc0], a1 = b1[oc0 + 1];
#pragma unroll
        for (int k = 0; k < 9; ++k) {
          a0 = fmaf(in[k], w1[oc0 * 9 + k], a0);
          a1 = fmaf(in[k], w1[(oc0 + 1) * 9 + k], a1);
        }
        a0 = ok1 ? fmaxf(a0, 0.f) : 0.f;   // OOB h1 pixel must be exactly 0
        a1 = ok1 ? fmaxf(a1, 0.f) : 0.f;
        u[j] = (unsigned)f2bf(a0) | ((unsigned)f2bf(a1) << 16);
      }
      *reinterpret_cast<uint4*>(actw + px * 128 + ((s ^ (px & 7)) << 4)) =
          make_uint4(u[0], u[1], u[2], u[3]);
    }
  }
  __syncthreads();  // full drain (vmcnt(0)) — weight pipeline starts clean

  int q = lane >> 4, n = lane & 15;
  f32x4 acc[4][4];
#pragma unroll
  for (int og = 0; og < 4; ++og)
#pragma unroll
    for (int g = 0; g < 4; ++g) acc[og][g] = (f32x4){0.f, 0.f, 0.f, 0.f};

  int plbase[4];
#pragma unroll
  for (int g = 0; g < 4; ++g)
    plbase[g] = (wave * 2 + (g >> 1)) * 34 + 16 * (g & 1) + n;
  const char* actb = (const char*)acts;

#pragma unroll
  for (int k = 0; k < 18; ++k) {
    asm volatile("s_waitcnt vmcnt(1)" ::: "memory");   // chunk k landed (in-order)
    __builtin_amdgcn_sched_barrier(0);
    __builtin_amdgcn_s_barrier();                      // all parts landed; NO drain
    __builtin_amdgcn_sched_barrier(0);
    if (k + 2 < 18) {                                  // slot (k+2)%3 free: read at k-1
      const unsigned short* src = wts + (size_t)(k + 2) * WCS + tid * 8;
      unsigned short* dstb = wbuf + ((k + 2) % 3) * WCS + wave * 512;
      __builtin_amdgcn_global_load_lds((const __attribute__((address_space(1))) void*)src,
                                       (__attribute__((address_space(3))) void*)dstb, 16, 0, 0);
    }
    const int tap = k >> 1, kc = k & 1;
    const int kyy = tap / 3, kxx = tap - kyy * 3;
    const char* wb = (const char*)(wbuf + (k % 3) * WCS);
    short8 af[4];
#pragma unroll
    for (int og = 0; og < 4; ++og) {
      int r = og * 16 + n;
      af[og] = *reinterpret_cast<const short8*>(wb + r * 64 + ((q ^ (r & 3)) * 16));
    }
#pragma unroll
    for (int g = 0; g < 4; ++g) {
      int pl = plbase[g] + kyy * 34 + kxx;
      int addr = pl * 128 + (((kc * 4 + q) ^ (pl & 7)) * 16);
      short8 bf = *reinterpret_cast<const short8*>(actb + addr);
#pragma unroll
      for (int og = 0; og < 4; ++og)
        acc[og][g] = __builtin_amdgcn_mfma_f32_16x16x32_bf16(af[og], bf, acc[og][g], 0, 0, 0);
    }
  }

  // ---- epilogue: acc -> LDS (swizzled NHWC tile) -> coalesced 16B stores ----
  __syncthreads();  // acts reads done; safe to reuse as output staging
  char* ob = (char*)acts;
#pragma unroll
  for (int og = 0; og < 4; ++og) {
    float b0 = bias[og * 16 + q * 4 + 0], b1v = bias[og * 16 + q * 4 + 1];
    float b2 = bias[og * 16 + q * 4 + 2], b3 = bias[og * 16 + q * 4 + 3];
#pragma unroll
    for (int g = 0; g < 4; ++g) {
      int pl = wave * 64 + g * 16 + n;
      f32x4 v = acc[og][g];
      float o0 = fmaxf(v.x + b0, 0.f), o1 = fmaxf(v.y + b1v, 0.f);
      float o2 = fmaxf(v.z + b2, 0.f), o3 = fmaxf(v.w + b3, 0.f);
      unsigned lo = (unsigned)f2bf(o0) | ((unsigned)f2bf(o1) << 16);
      unsigned hi = (unsigned)f2bf(o2) | ((unsigned)f2bf(o3) << 16);
      int lslot = og * 2 + (q >> 1);                   // logical 16B slot
      int wa = pl * 128 + (((lslot ^ (pl & 7)) << 4)) + ((q & 1) << 3);
      *reinterpret_cast<uint2*>(ob + wa) = make_uint2(lo, hi);
    }
  }
  __syncthreads();
  char* yb = (char*)ynhwc;
#pragma unroll
  for (int it = 0; it < 8; ++it) {
    int c = it * 256 + tid;                            // 2048 16-B chunks
    int pl = c >> 3, slot = c & 7;
    uint4 v = *reinterpret_cast<const uint4*>(ob + pl * 128 + ((slot ^ (pl & 7)) << 4));
    size_t gb = (((size_t)(r0 + (pl >> 5)) * 512) + c0 + (pl & 31)) * 128 + slot * 16;
    *reinterpret_cast<uint4*>(yb + gb) = v;
  }
}

// Shared acts staging for conv3: 344-px halo tile, 43 wave-issues of 1 KiB.
// LDS layout: [pix][8 slot'][8 ic] with slot' = slot ^ (pix&7).
__device__ inline void stage_acts(const unsigned short* __restrict__ xin,
                                  const unsigned short* __restrict__ zeros,
                                  unsigned short* acts, int r0, int c0,
                                  int wave, int lane) {
  for (int wi = wave; wi < 43; wi += 4) {
    int cidx = wi * 64 + lane;
    int pix = cidx >> 3, slotp = cidx & 7;
    int prow = pix / 34, pcol = pix - prow * 34;
    int gr = r0 + prow - 1, gc = c0 + pcol - 1;
    int slot = slotp ^ (pix & 7);
    bool ok = (pix < 340) & ((unsigned)gr < 512u) & ((unsigned)gc < 512u);
    const unsigned short* src = ok ? (xin + (((size_t)(gr * 512 + gc)) << 6) + slot * 8) : zeros;
    unsigned short* dstb = &acts[wi * 512];  // wave-uniform base
    __builtin_amdgcn_global_load_lds((const __attribute__((address_space(1))) void*)src,
                                     (__attribute__((address_space(3))) void*)dstb, 16, 0, 0);
  }
}

// ---------------- conv3 (MFMA): 64 -> 10, planar f32 out; weights fully LDS-resident ----------------
__global__ __launch_bounds__(256) void conv3_k(const unsigned short* __restrict__ xin,
                                               const unsigned short* __restrict__ wts,
                                               const float* __restrict__ bias,
                                               float* __restrict__ feats,
                                               const unsigned short* __restrict__ zeros) {
  __shared__ __align__(16) unsigned short acts[344 * 64];  // 44032 B
  __shared__ __align__(16) unsigned short wl[9216];        // 18432 B
  int tid = threadIdx.x;
  int lane = tid & 63, wave = tid >> 6;
  int logical = xcd_swz(blockIdx.x);
  int tilex = logical & 15, tiley = logical >> 4;
  int c0 = tilex * 32, r0 = tiley * 8;

  stage_acts(xin, zeros, acts, r0, c0, wave, lane);
  for (int wi = wave; wi < 18; wi += 4) {                  // all 18 KB of weights, once
    const unsigned short* src = wts + (size_t)wi * 512 + lane * 8;
    unsigned short* dstb = &wl[wi * 512];
    __builtin_amdgcn_global_load_lds((const __attribute__((address_space(1))) void*)src,
                                     (__attribute__((address_space(3))) void*)dstb, 16, 0, 0);
  }
  __syncthreads();

  int q = lane >> 4, n = lane & 15;
  f32x4 acc[4];
#pragma unroll
  for (int g = 0; g < 4; ++g) acc[g] = (f32x4){0.f, 0.f, 0.f, 0.f};
  int plbase[4];
#pragma unroll
  for (int g = 0; g < 4; ++g)
    plbase[g] = (wave * 2 + (g >> 1)) * 34 + 16 * (g & 1) + n;
  const char* actb = (const char*)acts;
  const char* wb0 = (const char*)wl;

#pragma unroll
  for (int k = 0; k < 18; ++k) {                           // no barriers, no waitcnts
    const int tap = k >> 1, kc = k & 1;
    const int kyy = tap / 3, kxx = tap - kyy * 3;
    short8 af = *reinterpret_cast<const short8*>(wb0 + k * 1024 + n * 64 + ((q ^ (n & 3)) * 16));
#pragma unroll
    for (int g = 0; g < 4; ++g) {
      int pl = plbase[g] + kyy * 34 + kxx;
      int addr = pl * 128 + (((kc * 4 + q) ^ (pl & 7)) * 16);
      short8 bf = *reinterpret_cast<const short8*>(actb + addr);
      acc[g] = __builtin_amdgcn_mfma_f32_16x16x32_bf16(af, bf, acc[g], 0, 0, 0);
    }
  }

  // ---- epilogue: acc -> LDS (stride-48 rows) -> coalesced 8B copies ----
  __syncthreads();
  char* ob = (char*)acts;
  float bb[4];
#pragma unroll
  for (int r2 = 0; r2 < 4; ++r2) {
    int oc = q * 4 + r2;
    bb[r2] = (oc < 10) ? bias[oc] : 0.f;
  }
#pragma unroll
  for (int g = 0; g < 4; ++g) {
    int pl = wave * 64 + g * 16 + n;
    f32x4 v = acc[g];
    float o0 = v.x + bb[0], o1 = v.y + bb[1], o2 = v.z + bb[2], o3 = v.w + bb[3];
    if (q < 2) {
      *reinterpret_cast<f32x4*>(ob + pl * 48 + q * 16) = (f32x4){o0, o1, o2, o3};
    } else if (q == 2) {
      *reinterpret_cast<float2*>(ob + pl * 48 + 32) = make_float2(o0, o1);
    }
  }
  __syncthreads();
  char* fb = (char*)feats;
#pragma unroll
  for (int it = 0; it < 5; ++it) {
    int c = it * 256 + tid;                            // 1280 8-B chunks (8 rows x 1280 B)
    int row = c / 160, ib = (c - row * 160) * 8;
    int px = ib / 40, off = ib - px * 40;
    uint2 v = *reinterpret_cast<const uint2*>(ob + (row * 32 + px) * 48 + off);
    size_t gb = (((size_t)(r0 + row) * 512) + c0) * 40 + (size_t)ib;
    *reinterpret_cast<uint2*>(fb + gb) = v;
  }
}

// ---------------- scatter: LDS accumulate -> per-block partials ----------------
__global__ __launch_bounds__(256) void scatter_k(const float* __restrict__ feats,  // [P][10]
                                                 const int* __restrict__ pix_rc,
                                                 const int* __restrict__ seg,
                                                 float* __restrict__ partials) {
  __shared__ float ls[NSP * 10];
  __shared__ float lc[NSP];
  int tid = threadIdx.x;
  for (int i = tid; i < NSP * 10; i += 256) ls[i] = 0.f;
  for (int i = tid; i < NSP; i += 256) lc[i] = 0.f;
  __syncthreads();

  constexpr int PER = P / SBLK;  // 1024
  int p0 = blockIdx.x * PER;
  for (int p = p0 + tid; p < p0 + PER; p += 256) {
    int r = pix_rc[2 * p], c = pix_rc[2 * p + 1];
    int s = seg[p];
    size_t gpix = (size_t)r * 512 + c;
    const float* fp = feats + gpix * 10;
    float v[10];
#pragma unroll
    for (int h2 = 0; h2 < 5; ++h2) {
      float2 t = *reinterpret_cast<const float2*>(fp + 2 * h2);
      v[2 * h2] = t.x;
      v[2 * h2 + 1] = t.y;
    }
#pragma unroll
    for (int ch = 0; ch < 10; ++ch) atomicAdd(&ls[s * 10 + ch], v[ch]);
    atomicAdd(&lc[s], 1.f);
  }
  __syncthreads();

  float* outp = partials + (size_t)blockIdx.x * (NSP * 11);
  for (int i = tid; i < NSP * 10; i += 256) outp[i] = ls[i];
  for (int i = tid; i < NSP; i += 256) outp[NSP * 10 + i] = lc[i];
}

// ---------------- finalize ----------------
__global__ __launch_bounds__(256) void finalize_k(const float* __restrict__ partials,
                                                  float* __restrict__ out) {
  int i = blockIdx.x * 256 + threadIdx.x;
  if (i >= NSP * 10) return;
  int sp = i / 10;
  float s = 0.f, cnt = 0.f;
  for (int bq = 0; bq < SBLK; ++bq) {
    const float* pp = partials + (size_t)bq * (NSP * 11);
    s += pp[i];
    cnt += pp[NSP * 10 + sp];
  }
  out[i] = s / fmaxf(cnt, 1.f);
}

extern "C" void kernel_launch(void* const* d_in, const int* in_sizes, int n_in,
                              void* d_out, int out_size, void* d_ws, size_t ws_size,
                              hipStream_t stream) {
  const float* raw = (const float*)d_in[0];
  const float* w1  = (const float*)d_in[1];
  const float* b1  = (const float*)d_in[2];
  const float* w2  = (const float*)d_in[3];
  const float* b2  = (const float*)d_in[4];
  const float* w3  = (const float*)d_in[5];
  const float* b3  = (const float*)d_in[6];
  const int* pix_rc = (const int*)d_in[7];
  const int* seg    = (const int*)d_in[8];
  float* out = (float*)d_out;

  char* ws = (char*)d_ws;
  unsigned short* h2   = (unsigned short*)(ws + 0);          // [P][64] bf16, 33.55 MB
  float* feats         = (float*)(ws + 33554432);            // [P][10] f32, 10.49 MB
  unsigned short* wt2s = (unsigned short*)(ws + 44040192);   // 36864 shorts = 73728 B
  unsigned short* wt3s = (unsigned short*)(ws + 44113920);   // 9216 shorts = 18432 B
  unsigned short* zeros = (unsigned short*)(ws + 44132352);  // 256 B zero stub
  float* partials      = (float*)(ws + 44132608);            // 256 * 11264 f32

  prep_k<<<180, 256, 0, stream>>>(w2, w3, wt2s, wt3s, zeros);
  conv2f_k<<<1024, 256, 0, stream>>>(raw, w1, b1, wt2s, b2, h2);
  conv3_k<<<1024, 256, 0, stream>>>(h2, wt3s, b3, feats, zeros);
  scatter_k<<<SBLK, 256, 0, stream>>>(feats, pix_rc, seg, partials);
  finalize_k<<<40, 256, 0, stream>>>(partials, out);
}

// Round 7
// 111.057 us; speedup vs baseline: 1.8491x; 1.8491x over previous
//
#include <hip/hip_runtime.h>

typedef __attribute__((ext_vector_type(8))) short short8;
typedef __attribute__((ext_vector_type(4))) float f32x4;

constexpr int H = 512, W = 512;
constexpr int P = H * W;     // 262144
constexpr int NSP = 1024;
constexpr int SBLK = 256;    // scatter partial blocks

__device__ inline unsigned short f2bf(float f) {
  unsigned u = __builtin_bit_cast(unsigned, f);
  unsigned r = (u + 0x7fffu + ((u >> 16) & 1u)) >> 16;  // RNE
  return (unsigned short)r;
}
__device__ inline float bflo(unsigned u) {  // low bf16 of packed u32 -> f32
  return __builtin_bit_cast(float, u << 16);
}
__device__ inline float bfhi(unsigned u) {  // high bf16 -> f32
  return __builtin_bit_cast(float, u & 0xffff0000u);
}

// XCD-band swizzle: 1024 blocks, 8 XCDs round-robin => XCD k owns logical
// ids [k*128,(k+1)*128) = pixel-row band [64k, 64k+64). Producer/consumer
// kernels use the SAME mapping so h1/h2 tiles are read from the writer's L2.
__device__ inline int xcd_swz(int b) { return (b & 7) * 128 + (b >> 3); }

// ---------------- conv1 (+fused weight prep): 1 -> 64, ReLU, NHWC bf16 out ----------------
// Blocks 0..179 additionally transform w2/w3 into staged-order bf16 with the
// baked-in XOR swizzle: chunk k (= tap*2+kc) of 16B-cells; cell t = (row r=t>>2,
// slot'=t&3); stored ic-slot s = slot'^(r&3).
__global__ __launch_bounds__(256) void conv1_k(const float* __restrict__ raw,
                                               const float* __restrict__ w1,
                                               const float* __restrict__ b1,
                                               const float* __restrict__ w2,
                                               const float* __restrict__ w3,
                                               unsigned short* __restrict__ h1,
                                               unsigned short* __restrict__ wt2s,
                                               unsigned short* __restrict__ wt3s,
                                               unsigned short* __restrict__ zeros) {
  int b = blockIdx.x;
  if (b == 0 && threadIdx.x < 128) zeros[threadIdx.x] = 0;  // 256-B zero stub
  if (b < 180) {                       // fused prep (same index math as old prep_k)
    int i = b * 256 + threadIdx.x;
    if (i < 36864) {                   // conv2: 18 chunks x 2048 shorts (64 oc rows)
      int k = i >> 11;
      int t = (i >> 3) & 255;
      int e = i & 7;
      int r = t >> 2, sp = t & 3, s = sp ^ (r & 3);
      int tap = k >> 1, ic = (k & 1) * 32 + s * 8 + e;
      wt2s[i] = f2bf(w2[r * 576 + ic * 9 + tap]);
    } else if (i < 46080) {            // conv3: 18 chunks x 512 shorts (16 rows, 10 real)
      int j = i - 36864;
      int k = j >> 9;
      int t = (j >> 3) & 63;
      int e = j & 7;
      int r = t >> 2, sp = t & 3, s = sp ^ (r & 3);
      int tap = k >> 1, ic = (k & 1) * 32 + s * 8 + e;
      wt3s[j] = (r < 10) ? f2bf(w3[r * 576 + ic * 9 + tap]) : (unsigned short)0;
    }
  }

  int pix = xcd_swz(b) * 256 + threadIdx.x;   // XCD k writes rows [64k,64k+64)
  int r = pix >> 9, c = pix & 511;
  float in[9];
#pragma unroll
  for (int ky = 0; ky < 3; ++ky)
#pragma unroll
    for (int kx = 0; kx < 3; ++kx) {
      int rr = r + ky - 1, cc = c + kx - 1;
      bool ok = ((unsigned)rr < (unsigned)H) && ((unsigned)cc < (unsigned)W);
      in[ky * 3 + kx] = ok ? raw[rr * W + cc] : 0.f;
    }
  unsigned out_u[32];
#pragma unroll
  for (int p2 = 0; p2 < 32; ++p2) {
    float a0 = b1[2 * p2], a1 = b1[2 * p2 + 1];
#pragma unroll
    for (int k = 0; k < 9; ++k) {
      a0 = fmaf(in[k], w1[(2 * p2) * 9 + k], a0);
      a1 = fmaf(in[k], w1[(2 * p2 + 1) * 9 + k], a1);
    }
    a0 = fmaxf(a0, 0.f);
    a1 = fmaxf(a1, 0.f);
    out_u[p2] = (unsigned)f2bf(a0) | ((unsigned)f2bf(a1) << 16);
  }
  uint4* dst = reinterpret_cast<uint4*>(h1 + (size_t)pix * 64);
#pragma unroll
  for (int i = 0; i < 8; ++i)
    dst[i] = make_uint4(out_u[4 * i], out_u[4 * i + 1], out_u[4 * i + 2], out_u[4 * i + 3]);
}

// Shared acts staging: 344-pixel halo tile (340 used), 43 wave-issues of 1 KiB.
// LDS layout: [pix][8 slot'][8 ic] with slot' = slot ^ (pix&7).
__device__ inline void stage_acts(const unsigned short* __restrict__ xin,
                                  const unsigned short* __restrict__ zeros,
                                  unsigned short* acts, int r0, int c0,
                                  int wave, int lane) {
  for (int wi = wave; wi < 43; wi += 4) {
    int cidx = wi * 64 + lane;
    int pix = cidx >> 3, slotp = cidx & 7;
    int prow = pix / 34, pcol = pix - prow * 34;
    int gr = r0 + prow - 1, gc = c0 + pcol - 1;
    int slot = slotp ^ (pix & 7);
    bool ok = (pix < 340) & ((unsigned)gr < 512u) & ((unsigned)gc < 512u);
    const unsigned short* src = ok ? (xin + (((size_t)(gr * 512 + gc)) << 6) + slot * 8) : zeros;
    unsigned short* dstb = &acts[wi * 512];  // wave-uniform base
    __builtin_amdgcn_global_load_lds((const __attribute__((address_space(1))) void*)src,
                                     (__attribute__((address_space(3))) void*)dstb, 16, 0, 0);
  }
}

// ---------------- conv2 (MFMA): 64 -> 64, ReLU, NHWC out; weight ring pipeline ----------------
__global__ __launch_bounds__(256) void conv2_k(const unsigned short* __restrict__ xin,
                                               const unsigned short* __restrict__ wts,
                                               const float* __restrict__ bias,
                                               unsigned short* __restrict__ ynhwc,
                                               const unsigned short* __restrict__ zeros) {
  constexpr int WCS = 2048;                                // chunk shorts (4 KiB)
  __shared__ __align__(16) unsigned short acts[344 * 64];  // 44032 B
  __shared__ __align__(16) unsigned short wbuf[3 * WCS];   // 12288 B
  int tid = threadIdx.x;
  int lane = tid & 63, wave = tid >> 6;
  int logical = xcd_swz(blockIdx.x);
  int tilex = logical & 15, tiley = logical >> 4;
  int c0 = tilex * 32, r0 = tiley * 8;

  stage_acts(xin, zeros, acts, r0, c0, wave, lane);
#pragma unroll
  for (int k0 = 0; k0 < 2; ++k0) {                         // prologue chunks 0,1
    const unsigned short* src = wts + (size_t)k0 * WCS + tid * 8;
    unsigned short* dstb = wbuf + k0 * WCS + wave * 512;
    __builtin_amdgcn_global_load_lds((const __attribute__((address_space(1))) void*)src,
                                     (__attribute__((address_space(3))) void*)dstb, 16, 0, 0);
  }
  __syncthreads();  // full drain — pipeline starts clean

  int q = lane >> 4, n = lane & 15;
  f32x4 acc[4][4];
#pragma unroll
  for (int og = 0; og < 4; ++og)
#pragma unroll
    for (int g = 0; g < 4; ++g) acc[og][g] = (f32x4){0.f, 0.f, 0.f, 0.f};

  int plbase[4];
#pragma unroll
  for (int g = 0; g < 4; ++g)
    plbase[g] = (wave * 2 + (g >> 1)) * 34 + 16 * (g & 1) + n;
  const char* actb = (const char*)acts;

#pragma unroll
  for (int k = 0; k < 18; ++k) {
    asm volatile("s_waitcnt vmcnt(1)" ::: "memory");   // own chunk-k part landed
    __builtin_amdgcn_sched_barrier(0);
    __builtin_amdgcn_s_barrier();                      // all parts landed; NO drain
    __builtin_amdgcn_sched_barrier(0);
    if (k + 2 < 18) {                                  // slot (k+2)%3 free: read at k-1
      const unsigned short* src = wts + (size_t)(k + 2) * WCS + tid * 8;
      unsigned short* dstb = wbuf + ((k + 2) % 3) * WCS + wave * 512;
      __builtin_amdgcn_global_load_lds((const __attribute__((address_space(1))) void*)src,
                                       (__attribute__((address_space(3))) void*)dstb, 16, 0, 0);
    }
    const int tap = k >> 1, kc = k & 1;
    const int kyy = tap / 3, kxx = tap - kyy * 3;
    const char* wb = (const char*)(wbuf + (k % 3) * WCS);
    short8 af[4];
#pragma unroll
    for (int og = 0; og < 4; ++og) {
      int r = og * 16 + n;
      af[og] = *reinterpret_cast<const short8*>(wb + r * 64 + ((q ^ (r & 3)) * 16));
    }
#pragma unroll
    for (int g = 0; g < 4; ++g) {
      int pl = plbase[g] + kyy * 34 + kxx;
      int addr = pl * 128 + (((kc * 4 + q) ^ (pl & 7)) * 16);
      short8 bf = *reinterpret_cast<const short8*>(actb + addr);
#pragma unroll
      for (int og = 0; og < 4; ++og)
        acc[og][g] = __builtin_amdgcn_mfma_f32_16x16x32_bf16(af[og], bf, acc[og][g], 0, 0, 0);
    }
  }

  // ---- epilogue: acc -> LDS (swizzled NHWC tile) -> coalesced 16B stores ----
  __syncthreads();  // acts reads done; safe to reuse as output staging
  char* ob = (char*)acts;
#pragma unroll
  for (int og = 0; og < 4; ++og) {
    float b0 = bias[og * 16 + q * 4 + 0], b1v = bias[og * 16 + q * 4 + 1];
    float b2 = bias[og * 16 + q * 4 + 2], b3 = bias[og * 16 + q * 4 + 3];
#pragma unroll
    for (int g = 0; g < 4; ++g) {
      int pl = wave * 64 + g * 16 + n;
      f32x4 v = acc[og][g];
      float o0 = fmaxf(v.x + b0, 0.f), o1 = fmaxf(v.y + b1v, 0.f);
      float o2 = fmaxf(v.z + b2, 0.f), o3 = fmaxf(v.w + b3, 0.f);
      unsigned lo = (unsigned)f2bf(o0) | ((unsigned)f2bf(o1) << 16);
      unsigned hi = (unsigned)f2bf(o2) | ((unsigned)f2bf(o3) << 16);
      int lslot = og * 2 + (q >> 1);                   // logical 16B slot
      int wa = pl * 128 + (((lslot ^ (pl & 7)) << 4)) + ((q & 1) << 3);
      *reinterpret_cast<uint2*>(ob + wa) = make_uint2(lo, hi);
    }
  }
  __syncthreads();
  char* yb = (char*)ynhwc;
#pragma unroll
  for (int it = 0; it < 8; ++it) {
    int c = it * 256 + tid;                            // 2048 16-B chunks
    int pl = c >> 3, slot = c & 7;
    uint4 v = *reinterpret_cast<const uint4*>(ob + pl * 128 + ((slot ^ (pl & 7)) << 4));
    size_t gb = (((size_t)(r0 + (pl >> 5)) * 512) + c0 + (pl & 31)) * 128 + slot * 16;
    *reinterpret_cast<uint4*>(yb + gb) = v;
  }
}

// ---------------- conv3 (MFMA): 64 -> 10, NHWC bf16 out [P][10]; weights LDS-resident ----------------
__global__ __launch_bounds__(256) void conv3_k(const unsigned short* __restrict__ xin,
                                               const unsigned short* __restrict__ wts,
                                               const float* __restrict__ bias,
                                               unsigned short* __restrict__ feats,
                                               const unsigned short* __restrict__ zeros) {
  __shared__ __align__(16) unsigned short acts[344 * 64];  // 44032 B
  __shared__ __align__(16) unsigned short wl[9216];        // 18432 B
  int tid = threadIdx.x;
  int lane = tid & 63, wave = tid >> 6;
  int logical = xcd_swz(blockIdx.x);
  int tilex = logical & 15, tiley = logical >> 4;
  int c0 = tilex * 32, r0 = tiley * 8;

  stage_acts(xin, zeros, acts, r0, c0, wave, lane);
  for (int wi = wave; wi < 18; wi += 4) {                  // all 18 KB of weights, once
    const unsigned short* src = wts + (size_t)wi * 512 + lane * 8;
    unsigned short* dstb = &wl[wi * 512];
    __builtin_amdgcn_global_load_lds((const __attribute__((address_space(1))) void*)src,
                                     (__attribute__((address_space(3))) void*)dstb, 16, 0, 0);
  }
  __syncthreads();

  int q = lane >> 4, n = lane & 15;
  f32x4 acc[4];
#pragma unroll
  for (int g = 0; g < 4; ++g) acc[g] = (f32x4){0.f, 0.f, 0.f, 0.f};
  int plbase[4];
#pragma unroll
  for (int g = 0; g < 4; ++g)
    plbase[g] = (wave * 2 + (g >> 1)) * 34 + 16 * (g & 1) + n;
  const char* actb = (const char*)acts;
  const char* wb0 = (const char*)wl;

#pragma unroll
  for (int k = 0; k < 18; ++k) {                           // no barriers, no waitcnts
    const int tap = k >> 1, kc = k & 1;
    const int kyy = tap / 3, kxx = tap - kyy * 3;
    short8 af = *reinterpret_cast<const short8*>(wb0 + k * 1024 + n * 64 + ((q ^ (n & 3)) * 16));
#pragma unroll
    for (int g = 0; g < 4; ++g) {
      int pl = plbase[g] + kyy * 34 + kxx;
      int addr = pl * 128 + (((kc * 4 + q) ^ (pl & 7)) * 16);
      short8 bf = *reinterpret_cast<const short8*>(actb + addr);
      acc[g] = __builtin_amdgcn_mfma_f32_16x16x32_bf16(af, bf, acc[g], 0, 0, 0);
    }
  }

  // ---- epilogue: acc -> bf16 in LDS (24B/px rows) -> coalesced 4B copies ----
  __syncthreads();
  char* ob = (char*)acts;
  float bb[4];
#pragma unroll
  for (int r2 = 0; r2 < 4; ++r2) {
    int oc = q * 4 + r2;
    bb[r2] = (oc < 10) ? bias[oc] : 0.f;
  }
#pragma unroll
  for (int g = 0; g < 4; ++g) {
    int pl = wave * 64 + g * 16 + n;
    f32x4 v = acc[g];
    float o0 = v.x + bb[0], o1 = v.y + bb[1], o2 = v.z + bb[2], o3 = v.w + bb[3];
    if (q < 2) {
      unsigned u0 = (unsigned)f2bf(o0) | ((unsigned)f2bf(o1) << 16);
      unsigned u1 = (unsigned)f2bf(o2) | ((unsigned)f2bf(o3) << 16);
      *reinterpret_cast<uint2*>(ob + pl * 24 + q * 8) = make_uint2(u0, u1);
    } else if (q == 2) {
      *reinterpret_cast<unsigned*>(ob + pl * 24 + 16) =
          (unsigned)f2bf(o0) | ((unsigned)f2bf(o1) << 16);
    }
  }
  __syncthreads();
  char* fb = (char*)feats;
#pragma unroll
  for (int it = 0; it < 5; ++it) {
    int c = it * 256 + tid;                            // 1280 4-B words (8 rows x 640 B)
    int row = c / 160, wb = c - row * 160;
    int byte = wb * 4;
    int px = byte / 20, off = byte - px * 20;
    unsigned v = *reinterpret_cast<const unsigned*>(ob + (row * 32 + px) * 24 + off);
    size_t gbyte = (((size_t)(r0 + row) * 512) + c0) * 20 + (size_t)byte;
    *reinterpret_cast<unsigned*>(fb + gbyte) = v;
  }
}

// ---------------- scatter: LDS accumulate -> per-block partials (bf16 feats) ----------------
__global__ __launch_bounds__(256) void scatter_k(const unsigned short* __restrict__ feats,  // [P][10] bf16
                                                 const int* __restrict__ pix_rc,
                                                 const int* __restrict__ seg,
                                                 float* __restrict__ partials) {
  __shared__ float ls[NSP * 10];
  __shared__ float lc[NSP];
  int tid = threadIdx.x;
  for (int i = tid; i < NSP * 10; i += 256) ls[i] = 0.f;
  for (int i = tid; i < NSP; i += 256) lc[i] = 0.f;
  __syncthreads();

  constexpr int PER = P / SBLK;  // 1024
  int p0 = blockIdx.x * PER;
  for (int p = p0 + tid; p < p0 + PER; p += 256) {
    int r = pix_rc[2 * p], c = pix_rc[2 * p + 1];
    int s = seg[p];
    size_t gpix = (size_t)r * 512 + c;
    const char* fp = (const char*)feats + gpix * 20;
    uint4 a = *reinterpret_cast<const uint4*>(fp);       // 16 B (4-aligned)
    unsigned e = *reinterpret_cast<const unsigned*>(fp + 16);
    float v[10];
    v[0] = bflo(a.x); v[1] = bfhi(a.x);
    v[2] = bflo(a.y); v[3] = bfhi(a.y);
    v[4] = bflo(a.z); v[5] = bfhi(a.z);
    v[6] = bflo(a.w); v[7] = bfhi(a.w);
    v[8] = bflo(e);   v[9] = bfhi(e);
#pragma unroll
    for (int ch = 0; ch < 10; ++ch) atomicAdd(&ls[s * 10 + ch], v[ch]);
    atomicAdd(&lc[s], 1.f);
  }
  __syncthreads();

  float* outp = partials + (size_t)blockIdx.x * (NSP * 11);
  for (int i = tid; i < NSP * 10; i += 256) outp[i] = ls[i];
  for (int i = tid; i < NSP; i += 256) outp[NSP * 10 + i] = lc[i];
}

// ---------------- finalize ----------------
__global__ __launch_bounds__(256) void finalize_k(const float* __restrict__ partials,
                                                  float* __restrict__ out) {
  int i = blockIdx.x * 256 + threadIdx.x;
  if (i >= NSP * 10) return;
  int sp = i / 10;
  float s = 0.f, cnt = 0.f;
  for (int bq = 0; bq < SBLK; ++bq) {
    const float* pp = partials + (size_t)bq * (NSP * 11);
    s += pp[i];
    cnt += pp[NSP * 10 + sp];
  }
  out[i] = s / fmaxf(cnt, 1.f);
}

extern "C" void kernel_launch(void* const* d_in, const int* in_sizes, int n_in,
                              void* d_out, int out_size, void* d_ws, size_t ws_size,
                              hipStream_t stream) {
  const float* raw = (const float*)d_in[0];
  const float* w1  = (const float*)d_in[1];
  const float* b1  = (const float*)d_in[2];
  const float* w2  = (const float*)d_in[3];
  const float* b2  = (const float*)d_in[4];
  const float* w3  = (const float*)d_in[5];
  const float* b3  = (const float*)d_in[6];
  const int* pix_rc = (const int*)d_in[7];
  const int* seg    = (const int*)d_in[8];
  float* out = (float*)d_out;

  char* ws = (char*)d_ws;
  unsigned short* h1   = (unsigned short*)(ws + 0);          // [P][64] bf16, 33.55 MB
  unsigned short* h2   = (unsigned short*)(ws + 33554432);   // [P][64] bf16, 33.55 MB
  unsigned short* feats = (unsigned short*)(ws + 67108864);  // [P][10] bf16, 5.25 MB
  unsigned short* wt2s = (unsigned short*)(ws + 72351744);   // 36864 shorts = 73728 B
  unsigned short* wt3s = (unsigned short*)(ws + 72425472);   // 9216 shorts = 18432 B
  unsigned short* zeros = (unsigned short*)(ws + 72443904);  // 256 B zero stub
  float* partials      = (float*)(ws + 72444160);            // 256 * 11264 f32

  conv1_k<<<1024, 256, 0, stream>>>(raw, w1, b1, w2, w3, h1, wt2s, wt3s, zeros);
  conv2_k<<<1024, 256, 0, stream>>>(h1, wt2s, b2, h2, zeros);
  conv3_k<<<1024, 256, 0, stream>>>(h2, wt3s, b3, feats, zeros);
  scatter_k<<<SBLK, 256, 0, stream>>>(feats, pix_rc, seg, partials);
  finalize_k<<<40, 256, 0, stream>>>(partials, out);
}

// Round 8
// 93.457 us; speedup vs baseline: 2.1973x; 1.1883x over previous
//
#include <hip/hip_runtime.h>

typedef __attribute__((ext_vector_type(8))) short short8;
typedef __attribute__((ext_vector_type(4))) float f32x4;

constexpr int H = 512, W = 512;
constexpr int P = H * W;     // 262144
constexpr int NSP = 1024;
constexpr int SBLK = 512;    // scatter partial sets
constexpr int FGRP = 16;     // finalize stage-A groups (32 sets each)

__device__ inline unsigned short f2bf(float f) {
  unsigned u = __builtin_bit_cast(unsigned, f);
  unsigned r = (u + 0x7fffu + ((u >> 16) & 1u)) >> 16;  // RNE
  return (unsigned short)r;
}
__device__ inline float bflo(unsigned u) { return __builtin_bit_cast(float, u << 16); }
__device__ inline float bfhi(unsigned u) { return __builtin_bit_cast(float, u & 0xffff0000u); }

// XCD-band swizzle (bijective: grid % 8 == 0). cpx = grid/8. Producer and
// consumer kernels map XCD k to the same pixel-row band [64k, 64k+64).
__device__ inline int xcd_swz(int b, int cpx) { return (b & 7) * cpx + (b >> 3); }

// ---------------- conv1 (+fused weight prep): 1 -> 64, ReLU, NHWC bf16 out ----------------
__global__ __launch_bounds__(256) void conv1_k(const float* __restrict__ raw,
                                               const float* __restrict__ w1,
                                               const float* __restrict__ b1,
                                               const float* __restrict__ w2,
                                               const float* __restrict__ w3,
                                               unsigned short* __restrict__ h1,
                                               unsigned short* __restrict__ wt2s,
                                               unsigned short* __restrict__ wt3s,
                                               unsigned short* __restrict__ zeros) {
  int b = blockIdx.x;
  if (b == 0 && threadIdx.x < 128) zeros[threadIdx.x] = 0;  // 256-B zero stub
  if (b < 180) {                       // weight prep (staged-order, baked-in swizzle)
    int i = b * 256 + threadIdx.x;
    if (i < 36864) {                   // conv2: 18 chunks x 2048 shorts (64 oc rows)
      int k = i >> 11;
      int t = (i >> 3) & 255;
      int e = i & 7;
      int r = t >> 2, sp = t & 3, s = sp ^ (r & 3);
      int tap = k >> 1, ic = (k & 1) * 32 + s * 8 + e;
      wt2s[i] = f2bf(w2[r * 576 + ic * 9 + tap]);
    } else if (i < 46080) {            // conv3: 18 chunks x 512 shorts (16 rows, 10 real)
      int j = i - 36864;
      int k = j >> 9;
      int t = (j >> 3) & 63;
      int e = j & 7;
      int r = t >> 2, sp = t & 3, s = sp ^ (r & 3);
      int tap = k >> 1, ic = (k & 1) * 32 + s * 8 + e;
      wt3s[j] = (r < 10) ? f2bf(w3[r * 576 + ic * 9 + tap]) : (unsigned short)0;
    }
  }

  int pix = xcd_swz(b, 128) * 256 + threadIdx.x;   // XCD k writes rows [64k,64k+64)
  int r = pix >> 9, c = pix & 511;
  float in[9];
#pragma unroll
  for (int ky = 0; ky < 3; ++ky)
#pragma unroll
    for (int kx = 0; kx < 3; ++kx) {
      int rr = r + ky - 1, cc = c + kx - 1;
      bool ok = ((unsigned)rr < (unsigned)H) && ((unsigned)cc < (unsigned)W);
      in[ky * 3 + kx] = ok ? raw[rr * W + cc] : 0.f;
    }
  unsigned out_u[32];
#pragma unroll
  for (int p2 = 0; p2 < 32; ++p2) {
    float a0 = b1[2 * p2], a1 = b1[2 * p2 + 1];
#pragma unroll
    for (int k = 0; k < 9; ++k) {
      a0 = fmaf(in[k], w1[(2 * p2) * 9 + k], a0);
      a1 = fmaf(in[k], w1[(2 * p2 + 1) * 9 + k], a1);
    }
    a0 = fmaxf(a0, 0.f);
    a1 = fmaxf(a1, 0.f);
    out_u[p2] = (unsigned)f2bf(a0) | ((unsigned)f2bf(a1) << 16);
  }
  uint4* dst = reinterpret_cast<uint4*>(h1 + (size_t)pix * 64);
#pragma unroll
  for (int i = 0; i < 8; ++i)
    dst[i] = make_uint4(out_u[4 * i], out_u[4 * i + 1], out_u[4 * i + 2], out_u[4 * i + 3]);
}

// Acts staging: 204-px halo tile (34 x 6), padded to 208; 26 wave-issues of 1 KiB.
// LDS layout: [pix][8 slot'][8 ic] with slot' = slot ^ (pix&7).
__device__ inline void stage_acts(const unsigned short* __restrict__ xin,
                                  const unsigned short* __restrict__ zeros,
                                  unsigned short* acts, int r0, int c0,
                                  int wave, int lane) {
  for (int wi = wave; wi < 26; wi += 4) {
    int cidx = wi * 64 + lane;
    int pix = cidx >> 3, slotp = cidx & 7;
    int prow = pix / 34, pcol = pix - prow * 34;
    int gr = r0 + prow - 1, gc = c0 + pcol - 1;
    int slot = slotp ^ (pix & 7);
    bool ok = (pix < 204) & ((unsigned)gr < 512u) & ((unsigned)gc < 512u);
    const unsigned short* src = ok ? (xin + (((size_t)(gr * 512 + gc)) << 6) + slot * 8) : zeros;
    unsigned short* dstb = &acts[wi * 512];  // wave-uniform base
    __builtin_amdgcn_global_load_lds((const __attribute__((address_space(1))) void*)src,
                                     (__attribute__((address_space(3))) void*)dstb, 16, 0, 0);
  }
}

// ---------------- conv2 (MFMA): 64 -> 64, ReLU, NHWC out; 32x4 tile, weight ring ----------------
__global__ __launch_bounds__(256) void conv2_k(const unsigned short* __restrict__ xin,
                                               const unsigned short* __restrict__ wts,
                                               const float* __restrict__ bias,
                                               unsigned short* __restrict__ ynhwc,
                                               const unsigned short* __restrict__ zeros) {
  constexpr int WCS = 2048;                                // weight chunk shorts (4 KiB)
  __shared__ __align__(16) unsigned short acts[208 * 64];  // 26624 B
  __shared__ __align__(16) unsigned short wbuf[3 * WCS];   // 12288 B  => 38912 B, 4 blk/CU
  int tid = threadIdx.x;
  int lane = tid & 63, wave = tid >> 6;
  int logical = xcd_swz(blockIdx.x, 256);
  int tilex = logical & 15, tiley = logical >> 4;
  int c0 = tilex * 32, r0 = tiley * 4;

  stage_acts(xin, zeros, acts, r0, c0, wave, lane);
#pragma unroll
  for (int k0 = 0; k0 < 2; ++k0) {                         // prologue chunks 0,1
    const unsigned short* src = wts + (size_t)k0 * WCS + tid * 8;
    unsigned short* dstb = wbuf + k0 * WCS + wave * 512;
    __builtin_amdgcn_global_load_lds((const __attribute__((address_space(1))) void*)src,
                                     (__attribute__((address_space(3))) void*)dstb, 16, 0, 0);
  }
  __syncthreads();  // full drain — pipeline starts clean

  int q = lane >> 4, n = lane & 15;
  f32x4 acc[4][2];
#pragma unroll
  for (int og = 0; og < 4; ++og)
#pragma unroll
    for (int g = 0; g < 2; ++g) acc[og][g] = (f32x4){0.f, 0.f, 0.f, 0.f};

  int plbase[2];
#pragma unroll
  for (int g = 0; g < 2; ++g) plbase[g] = wave * 34 + 16 * g + n;
  const char* actb = (const char*)acts;

#pragma unroll
  for (int k = 0; k < 18; ++k) {
    if (k == 17) {
      asm volatile("s_waitcnt vmcnt(0)" ::: "memory");  // last chunk must be landed
    } else {
      asm volatile("s_waitcnt vmcnt(1)" ::: "memory");  // own chunk-k part landed
    }
    __builtin_amdgcn_sched_barrier(0);
    __builtin_amdgcn_s_barrier();                      // all parts landed; NO drain
    __builtin_amdgcn_sched_barrier(0);
    if (k + 2 < 18) {                                  // slot (k+2)%3 free: read at k-1
      const unsigned short* src = wts + (size_t)(k + 2) * WCS + tid * 8;
      unsigned short* dstb = wbuf + ((k + 2) % 3) * WCS + wave * 512;
      __builtin_amdgcn_global_load_lds((const __attribute__((address_space(1))) void*)src,
                                       (__attribute__((address_space(3))) void*)dstb, 16, 0, 0);
    }
    const int tap = k >> 1, kc = k & 1;
    const int kyy = tap / 3, kxx = tap - kyy * 3;
    const char* wb = (const char*)(wbuf + (k % 3) * WCS);
    short8 af[4];
#pragma unroll
    for (int og = 0; og < 4; ++og) {
      int r = og * 16 + n;
      af[og] = *reinterpret_cast<const short8*>(wb + r * 64 + ((q ^ (r & 3)) * 16));
    }
#pragma unroll
    for (int g = 0; g < 2; ++g) {
      int pl = plbase[g] + kyy * 34 + kxx;
      int addr = pl * 128 + (((kc * 4 + q) ^ (pl & 7)) * 16);
      short8 bf = *reinterpret_cast<const short8*>(actb + addr);
#pragma unroll
      for (int og = 0; og < 4; ++og)
        acc[og][g] = __builtin_amdgcn_mfma_f32_16x16x32_bf16(af[og], bf, acc[og][g], 0, 0, 0);
    }
  }

  // ---- epilogue: acc -> LDS (swizzled NHWC tile, 128 px) -> coalesced 16B stores ----
  __syncthreads();  // acts reads done; safe to reuse as output staging
  char* ob = (char*)acts;
#pragma unroll
  for (int og = 0; og < 4; ++og) {
    float b0 = bias[og * 16 + q * 4 + 0], b1v = bias[og * 16 + q * 4 + 1];
    float b2 = bias[og * 16 + q * 4 + 2], b3 = bias[og * 16 + q * 4 + 3];
#pragma unroll
    for (int g = 0; g < 2; ++g) {
      int pl = wave * 32 + g * 16 + n;
      f32x4 v = acc[og][g];
      float o0 = fmaxf(v.x + b0, 0.f), o1 = fmaxf(v.y + b1v, 0.f);
      float o2 = fmaxf(v.z + b2, 0.f), o3 = fmaxf(v.w + b3, 0.f);
      unsigned lo = (unsigned)f2bf(o0) | ((unsigned)f2bf(o1) << 16);
      unsigned hi = (unsigned)f2bf(o2) | ((unsigned)f2bf(o3) << 16);
      int lslot = og * 2 + (q >> 1);                   // logical 16B slot
      int wa = pl * 128 + (((lslot ^ (pl & 7)) << 4)) + ((q & 1) << 3);
      *reinterpret_cast<uint2*>(ob + wa) = make_uint2(lo, hi);
    }
  }
  __syncthreads();
  char* yb = (char*)ynhwc;
#pragma unroll
  for (int it = 0; it < 4; ++it) {
    int c = it * 256 + tid;                            // 1024 16-B chunks
    int pl = c >> 3, slot = c & 7;
    uint4 v = *reinterpret_cast<const uint4*>(ob + pl * 128 + ((slot ^ (pl & 7)) << 4));
    size_t gb = (((size_t)(r0 + (pl >> 5)) * 512) + c0 + (pl & 31)) * 128 + slot * 16;
    *reinterpret_cast<uint4*>(yb + gb) = v;
  }
}

// ---------------- conv3 (MFMA): 64 -> 10, NHWC bf16 out [P][10]; 32x4 tile ----------------
__global__ __launch_bounds__(256) void conv3_k(const unsigned short* __restrict__ xin,
                                               const unsigned short* __restrict__ wts,
                                               const float* __restrict__ bias,
                                               unsigned short* __restrict__ feats,
                                               const unsigned short* __restrict__ zeros) {
  __shared__ __align__(16) unsigned short acts[208 * 64];  // 26624 B
  __shared__ __align__(16) unsigned short wl[9216];        // 18432 B => 45056 B, 3 blk/CU
  int tid = threadIdx.x;
  int lane = tid & 63, wave = tid >> 6;
  int logical = xcd_swz(blockIdx.x, 256);
  int tilex = logical & 15, tiley = logical >> 4;
  int c0 = tilex * 32, r0 = tiley * 4;

  stage_acts(xin, zeros, acts, r0, c0, wave, lane);
  for (int wi = wave; wi < 18; wi += 4) {                  // all 18 KB of weights, once
    const unsigned short* src = wts + (size_t)wi * 512 + lane * 8;
    unsigned short* dstb = &wl[wi * 512];
    __builtin_amdgcn_global_load_lds((const __attribute__((address_space(1))) void*)src,
                                     (__attribute__((address_space(3))) void*)dstb, 16, 0, 0);
  }
  __syncthreads();

  int q = lane >> 4, n = lane & 15;
  f32x4 acc[2];
#pragma unroll
  for (int g = 0; g < 2; ++g) acc[g] = (f32x4){0.f, 0.f, 0.f, 0.f};
  int plbase[2];
#pragma unroll
  for (int g = 0; g < 2; ++g) plbase[g] = wave * 34 + 16 * g + n;
  const char* actb = (const char*)acts;
  const char* wb0 = (const char*)wl;

#pragma unroll
  for (int k = 0; k < 18; ++k) {                           // no barriers, no waitcnts
    const int tap = k >> 1, kc = k & 1;
    const int kyy = tap / 3, kxx = tap - kyy * 3;
    short8 af = *reinterpret_cast<const short8*>(wb0 + k * 1024 + n * 64 + ((q ^ (n & 3)) * 16));
#pragma unroll
    for (int g = 0; g < 2; ++g) {
      int pl = plbase[g] + kyy * 34 + kxx;
      int addr = pl * 128 + (((kc * 4 + q) ^ (pl & 7)) * 16);
      short8 bf = *reinterpret_cast<const short8*>(actb + addr);
      acc[g] = __builtin_amdgcn_mfma_f32_16x16x32_bf16(af, bf, acc[g], 0, 0, 0);
    }
  }

  // ---- epilogue: acc -> bf16 in LDS (24B/px rows) -> coalesced 4B copies ----
  __syncthreads();
  char* ob = (char*)acts;
  float bb[4];
#pragma unroll
  for (int r2 = 0; r2 < 4; ++r2) {
    int oc = q * 4 + r2;
    bb[r2] = (oc < 10) ? bias[oc] : 0.f;
  }
#pragma unroll
  for (int g = 0; g < 2; ++g) {
    int pl = wave * 32 + g * 16 + n;
    f32x4 v = acc[g];
    float o0 = v.x + bb[0], o1 = v.y + bb[1], o2 = v.z + bb[2], o3 = v.w + bb[3];
    if (q < 2) {
      unsigned u0 = (unsigned)f2bf(o0) | ((unsigned)f2bf(o1) << 16);
      unsigned u1 = (unsigned)f2bf(o2) | ((unsigned)f2bf(o3) << 16);
      *reinterpret_cast<uint2*>(ob + pl * 24 + q * 8) = make_uint2(u0, u1);
    } else if (q == 2) {
      *reinterpret_cast<unsigned*>(ob + pl * 24 + 16) =
          (unsigned)f2bf(o0) | ((unsigned)f2bf(o1) << 16);
    }
  }
  __syncthreads();
  char* fb = (char*)feats;
  {
    int c = tid;                                       // 640 4-B words (4 rows x 640 B)
    for (int it = 0; it < 3 && c < 640; ++it, c += 256) {
      int row = c / 160, wb = c - row * 160;
      int byte = wb * 4;
      int px = byte / 20, off = byte - px * 20;
      unsigned v = *reinterpret_cast<const unsigned*>(ob + (row * 32 + px) * 24 + off);
      size_t gbyte = (((size_t)(r0 + row) * 512) + c0) * 20 + (size_t)byte;
      *reinterpret_cast<unsigned*>(fb + gbyte) = v;
    }
  }
}

// ---------------- scatter: LDS accumulate -> per-block partials (bf16 feats) ----------------
__global__ __launch_bounds__(256) void scatter_k(const unsigned short* __restrict__ feats,  // [P][10] bf16
                                                 const int* __restrict__ pix_rc,
                                                 const int* __restrict__ seg,
                                                 float* __restrict__ partials) {
  __shared__ float ls[NSP * 10];
  __shared__ float lc[NSP];
  int tid = threadIdx.x;
  for (int i = tid; i < NSP * 10; i += 256) ls[i] = 0.f;
  for (int i = tid; i < NSP; i += 256) lc[i] = 0.f;
  __syncthreads();

  constexpr int PER = P / SBLK;  // 512
  int p0 = blockIdx.x * PER;
  for (int p = p0 + tid; p < p0 + PER; p += 256) {
    int r = pix_rc[2 * p], c = pix_rc[2 * p + 1];
    int s = seg[p];
    size_t gpix = (size_t)r * 512 + c;
    const char* fp = (const char*)feats + gpix * 20;
    uint4 a = *reinterpret_cast<const uint4*>(fp);       // 16 B (4-aligned)
    unsigned e = *reinterpret_cast<const unsigned*>(fp + 16);
    float v[10];
    v[0] = bflo(a.x); v[1] = bfhi(a.x);
    v[2] = bflo(a.y); v[3] = bfhi(a.y);
    v[4] = bflo(a.z); v[5] = bfhi(a.z);
    v[6] = bflo(a.w); v[7] = bfhi(a.w);
    v[8] = bflo(e);   v[9] = bfhi(e);
#pragma unroll
    for (int ch = 0; ch < 10; ++ch) atomicAdd(&ls[s * 10 + ch], v[ch]);
    atomicAdd(&lc[s], 1.f);
  }
  __syncthreads();

  float* outp = partials + (size_t)blockIdx.x * (NSP * 11);
  for (int i = tid; i < NSP * 10; i += 256) outp[i] = ls[i];
  for (int i = tid; i < NSP; i += 256) outp[NSP * 10 + i] = lc[i];
}

// ---------------- finalize stage A: 16 groups x 32 sets -> partials2 ----------------
__global__ __launch_bounds__(256) void finA_k(const float* __restrict__ partials,
                                              float* __restrict__ partials2) {
  int g = blockIdx.x / 44;                        // 44 blocks/group (44*256 = 11264)
  int e = (blockIdx.x - g * 44) * 256 + threadIdx.x;
  const float* base = partials + (size_t)(g * 32) * (NSP * 11) + e;
  float s = 0.f;
#pragma unroll 8
  for (int k = 0; k < 32; ++k) s += base[(size_t)k * (NSP * 11)];
  partials2[(size_t)g * (NSP * 11) + e] = s;
}

// ---------------- finalize stage B: sum 16 groups, divide ----------------
__global__ __launch_bounds__(256) void finB_k(const float* __restrict__ partials2,
                                              float* __restrict__ out) {
  int i = blockIdx.x * 256 + threadIdx.x;
  if (i >= NSP * 10) return;
  int sp = i / 10;
  float s = 0.f, cnt = 0.f;
#pragma unroll
  for (int g = 0; g < FGRP; ++g) {
    const float* pp = partials2 + (size_t)g * (NSP * 11);
    s += pp[i];
    cnt += pp[NSP * 10 + sp];
  }
  out[i] = s / fmaxf(cnt, 1.f);
}

extern "C" void kernel_launch(void* const* d_in, const int* in_sizes, int n_in,
                              void* d_out, int out_size, void* d_ws, size_t ws_size,
                              hipStream_t stream) {
  const float* raw = (const float*)d_in[0];
  const float* w1  = (const float*)d_in[1];
  const float* b1  = (const float*)d_in[2];
  const float* w2  = (const float*)d_in[3];
  const float* b2  = (const float*)d_in[4];
  const float* w3  = (const float*)d_in[5];
  const float* b3  = (const float*)d_in[6];
  const int* pix_rc = (const int*)d_in[7];
  const int* seg    = (const int*)d_in[8];
  float* out = (float*)d_out;

  char* ws = (char*)d_ws;
  unsigned short* h1   = (unsigned short*)(ws + 0);          // [P][64] bf16, 33.55 MB
  unsigned short* h2   = (unsigned short*)(ws + 33554432);   // [P][64] bf16, 33.55 MB
  unsigned short* feats = (unsigned short*)(ws + 67108864);  // [P][10] bf16, 5.25 MB
  unsigned short* wt2s = (unsigned short*)(ws + 72351744);   // 36864 shorts = 73728 B
  unsigned short* wt3s = (unsigned short*)(ws + 72425472);   // 9216 shorts = 18432 B
  unsigned short* zeros = (unsigned short*)(ws + 72443904);  // 256 B zero stub
  // partials live in h1's region (h1 dead once conv2 completes; scatter runs after conv3)
  float* partials  = (float*)(ws + 0);                       // 512 * 11264 f32 = 23.07 MB
  float* partials2 = (float*)(ws + 23068672);                // 16 * 11264 f32 = 0.72 MB

  conv1_k<<<1024, 256, 0, stream>>>(raw, w1, b1, w2, w3, h1, wt2s, wt3s, zeros);
  conv2_k<<<2048, 256, 0, stream>>>(h1, wt2s, b2, h2, zeros);
  conv3_k<<<2048, 256, 0, stream>>>(h2, wt3s, b3, feats, zeros);
  scatter_k<<<SBLK, 256, 0, stream>>>(feats, pix_rc, seg, partials);
  finA_k<<<FGRP * 44, 256, 0, stream>>>(partials, partials2);
  finB_k<<<40, 256, 0, stream>>>(partials2, out);
}

// Round 9
// 84.620 us; speedup vs baseline: 2.4268x; 1.1044x over previous
//
#include <hip/hip_runtime.h>

typedef __attribute__((ext_vector_type(8))) short short8;
typedef __attribute__((ext_vector_type(4))) float f32x4;

constexpr int H = 512, W = 512;
constexpr int P = H * W;     // 262144
constexpr int NSP = 1024;
constexpr int SBLK = 512;    // scatter partial sets
constexpr int FGRP = 16;     // finalize stage-A groups (32 sets each)

__device__ inline unsigned short f2bf(float f) {
  unsigned u = __builtin_bit_cast(unsigned, f);
  unsigned r = (u + 0x7fffu + ((u >> 16) & 1u)) >> 16;  // RNE
  return (unsigned short)r;
}
__device__ inline float bflo(unsigned u) { return __builtin_bit_cast(float, u << 16); }
__device__ inline float bfhi(unsigned u) { return __builtin_bit_cast(float, u & 0xffff0000u); }

// XCD-band swizzle (bijective: grid % 8 == 0). cpx = grid/8. Producer and
// consumer kernels map XCD k to the same pixel-row band.
__device__ inline int xcd_swz(int b, int cpx) { return (b & 7) * cpx + (b >> 3); }

// ---------------- prep: weights -> staged-order bf16 with baked-in swizzle ----------------
__global__ __launch_bounds__(256) void prep_k(const float* __restrict__ w2,
                                              const float* __restrict__ w3,
                                              unsigned short* __restrict__ wt2s,
                                              unsigned short* __restrict__ wt3s,
                                              unsigned short* __restrict__ zeros) {
  if (blockIdx.x == 0 && threadIdx.x < 128) zeros[threadIdx.x] = 0;  // 256-B zero stub
  int i = blockIdx.x * 256 + threadIdx.x;
  if (i < 36864) {                     // conv2: 18 chunks x 2048 shorts (64 oc rows)
    int k = i >> 11;
    int t = (i >> 3) & 255;
    int e = i & 7;
    int r = t >> 2, sp = t & 3, s = sp ^ (r & 3);
    int tap = k >> 1, ic = (k & 1) * 32 + s * 8 + e;
    wt2s[i] = f2bf(w2[r * 576 + ic * 9 + tap]);
  } else if (i < 46080) {              // conv3: 18 chunks x 512 shorts (16 rows, 10 real)
    int j = i - 36864;
    int k = j >> 9;
    int t = (j >> 3) & 63;
    int e = j & 7;
    int r = t >> 2, sp = t & 3, s = sp ^ (r & 3);
    int tap = k >> 1, ic = (k & 1) * 32 + s * 8 + e;
    wt3s[j] = (r < 10) ? f2bf(w3[r * 576 + ic * 9 + tap]) : (unsigned short)0;
  }
}

// Acts staging (conv3 only): 204-px halo tile padded to 208; 26 x 1 KiB DMA.
// LDS layout: [pix][8 slot'][8 ic] with slot' = slot ^ (pix&7).
__device__ inline void stage_acts(const unsigned short* __restrict__ xin,
                                  const unsigned short* __restrict__ zeros,
                                  unsigned short* acts, int r0, int c0,
                                  int wave, int lane) {
  for (int wi = wave; wi < 26; wi += 4) {
    int cidx = wi * 64 + lane;
    int pix = cidx >> 3, slotp = cidx & 7;
    int prow = pix / 34, pcol = pix - prow * 34;
    int gr = r0 + prow - 1, gc = c0 + pcol - 1;
    int slot = slotp ^ (pix & 7);
    bool ok = (pix < 204) & ((unsigned)gr < 512u) & ((unsigned)gc < 512u);
    const unsigned short* src = ok ? (xin + (((size_t)(gr * 512 + gc)) << 6) + slot * 8) : zeros;
    unsigned short* dstb = &acts[wi * 512];  // wave-uniform base
    __builtin_amdgcn_global_load_lds((const __attribute__((address_space(1))) void*)src,
                                     (__attribute__((address_space(3))) void*)dstb, 16, 0, 0);
  }
}

// ---------------- conv2 (fused conv1-via-MFMA + conv2 MFMA): raw -> h2 NHWC bf16 ----------------
// Phase 1: conv1 as K=9 (padded to 32) MFMA GEMM on the 208-px halo tile, h1
// written straight into swizzled acts LDS (never global). Phase 2: 18-step
// weight-ring MFMA k-loop (unchanged from R8).
__global__ __launch_bounds__(256) void conv2_k(const float* __restrict__ raw,
                                               const float* __restrict__ w1,
                                               const float* __restrict__ b1,
                                               const unsigned short* __restrict__ wts,
                                               const float* __restrict__ bias,
                                               unsigned short* __restrict__ ynhwc) {
  constexpr int WCS = 2048;                                // weight chunk shorts (4 KiB)
  __shared__ __align__(16) unsigned short acts[208 * 64];  // 26624 B
  __shared__ __align__(16) unsigned short wbuf[3 * WCS];   // 12288 B
  __shared__ float rawt[9 * 36];                           // 1296 B => 40208 B, 4 blk/CU
  int tid = threadIdx.x;
  int lane = tid & 63, wave = tid >> 6;
  int logical = xcd_swz(blockIdx.x, 256);
  int tilex = logical & 15, tiley = logical >> 4;
  int c0 = tilex * 32, r0 = tiley * 4;

  // ---- issue weight prologue chunks 0,1 (land under phase 1) ----
#pragma unroll
  for (int k0 = 0; k0 < 2; ++k0) {
    const unsigned short* src = wts + (size_t)k0 * WCS + tid * 8;
    unsigned short* dstb = wbuf + k0 * WCS + wave * 512;
    __builtin_amdgcn_global_load_lds((const __attribute__((address_space(1))) void*)src,
                                     (__attribute__((address_space(3))) void*)dstb, 16, 0, 0);
  }
  // ---- stage raw halo-of-halo [9 rows][36 cols] (rows r0-2 .. r0+6) ----
  for (int i = tid; i < 324; i += 256) {
    int rr = i / 36, cc = i - rr * 36;
    int gr = r0 + rr - 2, gc = c0 + cc - 2;
    bool ok = ((unsigned)gr < 512u) && ((unsigned)gc < 512u);
    rawt[i] = ok ? raw[gr * 512 + gc] : 0.f;
  }

  int q = lane >> 4, n = lane & 15;
  // A-frag for conv1: row = oc (wave*16+n), k = q*8+e; taps 0-8 real, rest 0.
  short8 a1f;
  {
    short av[8];
#pragma unroll
    for (int e = 0; e < 8; ++e) av[e] = 0;
    int oc = wave * 16 + n;
    if (q == 0) {
#pragma unroll
      for (int e = 0; e < 8; ++e) av[e] = (short)f2bf(w1[oc * 9 + e]);
    } else if (q == 1) {
      av[0] = (short)f2bf(w1[oc * 9 + 8]);
    }
    a1f = (short8){av[0], av[1], av[2], av[3], av[4], av[5], av[6], av[7]};
  }
  float bb1[4];
#pragma unroll
  for (int r2 = 0; r2 < 4; ++r2) bb1[r2] = b1[wave * 16 + q * 4 + r2];
  __syncthreads();  // rawt visible (wbuf 0,1 also drained)

  // ---- phase 1: conv1 via MFMA, 13 px-tiles, og = wave ----
  char* actw = (char*)acts;
  for (int t = 0; t < 13; ++t) {
    int px = t * 16 + n;
    int prow = px / 34, pcol = px - prow * 34;
    short bv[8];
#pragma unroll
    for (int e = 0; e < 8; ++e) bv[e] = 0;
    if (q == 0) {
#pragma unroll
      for (int e = 0; e < 8; ++e) {
        int dy = e / 3, dx = e - dy * 3;  // taps 0..7
        bv[e] = (short)f2bf(rawt[(prow + dy) * 36 + pcol + dx]);
      }
    } else if (q == 1) {
      bv[0] = (short)f2bf(rawt[(prow + 2) * 36 + pcol + 2]);  // tap 8
    }
    short8 b1f = (short8){bv[0], bv[1], bv[2], bv[3], bv[4], bv[5], bv[6], bv[7]};
    f32x4 d = __builtin_amdgcn_mfma_f32_16x16x32_bf16(a1f, b1f,
                                                       (f32x4){0.f, 0.f, 0.f, 0.f}, 0, 0, 0);
    int gr1 = r0 + prow - 1, gc1 = c0 + pcol - 1;
    bool ok1 = ((unsigned)gr1 < 512u) && ((unsigned)gc1 < 512u);
    float o0 = ok1 ? fmaxf(d.x + bb1[0], 0.f) : 0.f;
    float o1 = ok1 ? fmaxf(d.y + bb1[1], 0.f) : 0.f;
    float o2 = ok1 ? fmaxf(d.z + bb1[2], 0.f) : 0.f;
    float o3 = ok1 ? fmaxf(d.w + bb1[3], 0.f) : 0.f;
    unsigned lo = (unsigned)f2bf(o0) | ((unsigned)f2bf(o1) << 16);
    unsigned hi = (unsigned)f2bf(o2) | ((unsigned)f2bf(o3) << 16);
    int wa = px * 128 + ((((wave * 2 + (q >> 1)) ^ (px & 7)) << 4)) + ((q & 1) << 3);
    *reinterpret_cast<uint2*>(actw + wa) = make_uint2(lo, hi);
  }
  __syncthreads();  // acts complete; vmcnt outstanding = 0 — ring starts clean

  // ---- phase 2: 18-step weight-ring k-loop ----
  f32x4 acc[4][2];
#pragma unroll
  for (int og = 0; og < 4; ++og)
#pragma unroll
    for (int g = 0; g < 2; ++g) acc[og][g] = (f32x4){0.f, 0.f, 0.f, 0.f};

  int plbase[2];
#pragma unroll
  for (int g = 0; g < 2; ++g) plbase[g] = wave * 34 + 16 * g + n;
  const char* actb = (const char*)acts;

#pragma unroll
  for (int k = 0; k < 18; ++k) {
    if (k == 17) {
      asm volatile("s_waitcnt vmcnt(0)" ::: "memory");  // last chunk landed
    } else {
      asm volatile("s_waitcnt vmcnt(1)" ::: "memory");  // chunk k landed (in-order)
    }
    __builtin_amdgcn_sched_barrier(0);
    __builtin_amdgcn_s_barrier();                      // all parts landed; NO drain
    __builtin_amdgcn_sched_barrier(0);
    if (k + 2 < 18) {                                  // slot (k+2)%3 free: read at k-1
      const unsigned short* src = wts + (size_t)(k + 2) * WCS + tid * 8;
      unsigned short* dstb = wbuf + ((k + 2) % 3) * WCS + wave * 512;
      __builtin_amdgcn_global_load_lds((const __attribute__((address_space(1))) void*)src,
                                       (__attribute__((address_space(3))) void*)dstb, 16, 0, 0);
    }
    const int tap = k >> 1, kc = k & 1;
    const int kyy = tap / 3, kxx = tap - kyy * 3;
    const char* wb = (const char*)(wbuf + (k % 3) * WCS);
    short8 af[4];
#pragma unroll
    for (int og = 0; og < 4; ++og) {
      int r = og * 16 + n;
      af[og] = *reinterpret_cast<const short8*>(wb + r * 64 + ((q ^ (r & 3)) * 16));
    }
#pragma unroll
    for (int g = 0; g < 2; ++g) {
      int pl = plbase[g] + kyy * 34 + kxx;
      int addr = pl * 128 + (((kc * 4 + q) ^ (pl & 7)) * 16);
      short8 bf = *reinterpret_cast<const short8*>(actb + addr);
#pragma unroll
      for (int og = 0; og < 4; ++og)
        acc[og][g] = __builtin_amdgcn_mfma_f32_16x16x32_bf16(af[og], bf, acc[og][g], 0, 0, 0);
    }
  }

  // ---- epilogue: acc -> LDS (swizzled NHWC tile, 128 px) -> coalesced 16B stores ----
  __syncthreads();  // acts reads done; safe to reuse as output staging
  char* ob = (char*)acts;
#pragma unroll
  for (int og = 0; og < 4; ++og) {
    float b0 = bias[og * 16 + q * 4 + 0], b1v = bias[og * 16 + q * 4 + 1];
    float b2 = bias[og * 16 + q * 4 + 2], b3 = bias[og * 16 + q * 4 + 3];
#pragma unroll
    for (int g = 0; g < 2; ++g) {
      int pl = wave * 32 + g * 16 + n;
      f32x4 v = acc[og][g];
      float o0 = fmaxf(v.x + b0, 0.f), o1 = fmaxf(v.y + b1v, 0.f);
      float o2 = fmaxf(v.z + b2, 0.f), o3 = fmaxf(v.w + b3, 0.f);
      unsigned lo = (unsigned)f2bf(o0) | ((unsigned)f2bf(o1) << 16);
      unsigned hi = (unsigned)f2bf(o2) | ((unsigned)f2bf(o3) << 16);
      int lslot = og * 2 + (q >> 1);                   // logical 16B slot
      int wa = pl * 128 + (((lslot ^ (pl & 7)) << 4)) + ((q & 1) << 3);
      *reinterpret_cast<uint2*>(ob + wa) = make_uint2(lo, hi);
    }
  }
  __syncthreads();
  char* yb = (char*)ynhwc;
#pragma unroll
  for (int it = 0; it < 4; ++it) {
    int c = it * 256 + tid;                            // 1024 16-B chunks
    int pl = c >> 3, slot = c & 7;
    uint4 v = *reinterpret_cast<const uint4*>(ob + pl * 128 + ((slot ^ (pl & 7)) << 4));
    size_t gb = (((size_t)(r0 + (pl >> 5)) * 512) + c0 + (pl & 31)) * 128 + slot * 16;
    *reinterpret_cast<uint4*>(yb + gb) = v;
  }
}

// ---------------- conv3 (MFMA): 64 -> 10, NHWC bf16 out [P][10]; 32x4 tile ----------------
__global__ __launch_bounds__(256) void conv3_k(const unsigned short* __restrict__ xin,
                                               const unsigned short* __restrict__ wts,
                                               const float* __restrict__ bias,
                                               unsigned short* __restrict__ feats,
                                               const unsigned short* __restrict__ zeros) {
  __shared__ __align__(16) unsigned short acts[208 * 64];  // 26624 B
  __shared__ __align__(16) unsigned short wl[9216];        // 18432 B => 45056 B, 3 blk/CU
  int tid = threadIdx.x;
  int lane = tid & 63, wave = tid >> 6;
  int logical = xcd_swz(blockIdx.x, 256);
  int tilex = logical & 15, tiley = logical >> 4;
  int c0 = tilex * 32, r0 = tiley * 4;

  stage_acts(xin, zeros, acts, r0, c0, wave, lane);
  for (int wi = wave; wi < 18; wi += 4) {                  // all 18 KB of weights, once
    const unsigned short* src = wts + (size_t)wi * 512 + lane * 8;
    unsigned short* dstb = &wl[wi * 512];
    __builtin_amdgcn_global_load_lds((const __attribute__((address_space(1))) void*)src,
                                     (__attribute__((address_space(3))) void*)dstb, 16, 0, 0);
  }
  __syncthreads();

  int q = lane >> 4, n = lane & 15;
  f32x4 acc[2];
#pragma unroll
  for (int g = 0; g < 2; ++g) acc[g] = (f32x4){0.f, 0.f, 0.f, 0.f};
  int plbase[2];
#pragma unroll
  for (int g = 0; g < 2; ++g) plbase[g] = wave * 34 + 16 * g + n;
  const char* actb = (const char*)acts;
  const char* wb0 = (const char*)wl;

#pragma unroll
  for (int k = 0; k < 18; ++k) {                           // no barriers, no waitcnts
    const int tap = k >> 1, kc = k & 1;
    const int kyy = tap / 3, kxx = tap - kyy * 3;
    short8 af = *reinterpret_cast<const short8*>(wb0 + k * 1024 + n * 64 + ((q ^ (n & 3)) * 16));
#pragma unroll
    for (int g = 0; g < 2; ++g) {
      int pl = plbase[g] + kyy * 34 + kxx;
      int addr = pl * 128 + (((kc * 4 + q) ^ (pl & 7)) * 16);
      short8 bf = *reinterpret_cast<const short8*>(actb + addr);
      acc[g] = __builtin_amdgcn_mfma_f32_16x16x32_bf16(af, bf, acc[g], 0, 0, 0);
    }
  }

  // ---- epilogue: acc -> bf16 in LDS (24B/px rows) -> coalesced 4B copies ----
  __syncthreads();
  char* ob = (char*)acts;
  float bb[4];
#pragma unroll
  for (int r2 = 0; r2 < 4; ++r2) {
    int oc = q * 4 + r2;
    bb[r2] = (oc < 10) ? bias[oc] : 0.f;
  }
#pragma unroll
  for (int g = 0; g < 2; ++g) {
    int pl = wave * 32 + g * 16 + n;
    f32x4 v = acc[g];
    float o0 = v.x + bb[0], o1 = v.y + bb[1], o2 = v.z + bb[2], o3 = v.w + bb[3];
    if (q < 2) {
      unsigned u0 = (unsigned)f2bf(o0) | ((unsigned)f2bf(o1) << 16);
      unsigned u1 = (unsigned)f2bf(o2) | ((unsigned)f2bf(o3) << 16);
      *reinterpret_cast<uint2*>(ob + pl * 24 + q * 8) = make_uint2(u0, u1);
    } else if (q == 2) {
      *reinterpret_cast<unsigned*>(ob + pl * 24 + 16) =
          (unsigned)f2bf(o0) | ((unsigned)f2bf(o1) << 16);
    }
  }
  __syncthreads();
  char* fb = (char*)feats;
  {
    int c = tid;                                       // 640 4-B words (4 rows x 640 B)
    for (int it = 0; it < 3 && c < 640; ++it, c += 256) {
      int row = c / 160, wb = c - row * 160;
      int byte = wb * 4;
      int px = byte / 20, off = byte - px * 20;
      unsigned v = *reinterpret_cast<const unsigned*>(ob + (row * 32 + px) * 24 + off);
      size_t gbyte = (((size_t)(r0 + row) * 512) + c0) * 20 + (size_t)byte;
      *reinterpret_cast<unsigned*>(fb + gbyte) = v;
    }
  }
}

// ---------------- scatter: LDS accumulate -> per-block partials (bf16 feats) ----------------
__global__ __launch_bounds__(256) void scatter_k(const unsigned short* __restrict__ feats,  // [P][10] bf16
                                                 const int* __restrict__ pix_rc,
                                                 const int* __restrict__ seg,
                                                 float* __restrict__ partials) {
  __shared__ float ls[NSP * 10];
  __shared__ float lc[NSP];
  int tid = threadIdx.x;
  for (int i = tid; i < NSP * 10; i += 256) ls[i] = 0.f;
  for (int i = tid; i < NSP; i += 256) lc[i] = 0.f;
  __syncthreads();

  constexpr int PER = P / SBLK;  // 512
  int p0 = blockIdx.x * PER;
  for (int p = p0 + tid; p < p0 + PER; p += 256) {
    int r = pix_rc[2 * p], c = pix_rc[2 * p + 1];
    int s = seg[p];
    size_t gpix = (size_t)r * 512 + c;
    const char* fp = (const char*)feats + gpix * 20;
    uint4 a = *reinterpret_cast<const uint4*>(fp);       // 16 B (4-aligned)
    unsigned e = *reinterpret_cast<const unsigned*>(fp + 16);
    float v[10];
    v[0] = bflo(a.x); v[1] = bfhi(a.x);
    v[2] = bflo(a.y); v[3] = bfhi(a.y);
    v[4] = bflo(a.z); v[5] = bfhi(a.z);
    v[6] = bflo(a.w); v[7] = bfhi(a.w);
    v[8] = bflo(e);   v[9] = bfhi(e);
#pragma unroll
    for (int ch = 0; ch < 10; ++ch) atomicAdd(&ls[s * 10 + ch], v[ch]);
    atomicAdd(&lc[s], 1.f);
  }
  __syncthreads();

  float* outp = partials + (size_t)blockIdx.x * (NSP * 11);
  for (int i = tid; i < NSP * 10; i += 256) outp[i] = ls[i];
  for (int i = tid; i < NSP; i += 256) outp[NSP * 10 + i] = lc[i];
}

// ---------------- finalize stage A: 16 groups x 32 sets -> partials2 ----------------
__global__ __launch_bounds__(256) void finA_k(const float* __restrict__ partials,
                                              float* __restrict__ partials2) {
  int g = blockIdx.x / 44;                        // 44 blocks/group (44*256 = 11264)
  int e = (blockIdx.x - g * 44) * 256 + threadIdx.x;
  const float* base = partials + (size_t)(g * 32) * (NSP * 11) + e;
  float s = 0.f;
#pragma unroll 8
  for (int k = 0; k < 32; ++k) s += base[(size_t)k * (NSP * 11)];
  partials2[(size_t)g * (NSP * 11) + e] = s;
}

// ---------------- finalize stage B: sum 16 groups, divide ----------------
__global__ __launch_bounds__(256) void finB_k(const float* __restrict__ partials2,
                                              float* __restrict__ out) {
  int i = blockIdx.x * 256 + threadIdx.x;
  if (i >= NSP * 10) return;
  int sp = i / 10;
  float s = 0.f, cnt = 0.f;
#pragma unroll
  for (int g = 0; g < FGRP; ++g) {
    const float* pp = partials2 + (size_t)g * (NSP * 11);
    s += pp[i];
    cnt += pp[NSP * 10 + sp];
  }
  out[i] = s / fmaxf(cnt, 1.f);
}

extern "C" void kernel_launch(void* const* d_in, const int* in_sizes, int n_in,
                              void* d_out, int out_size, void* d_ws, size_t ws_size,
                              hipStream_t stream) {
  const float* raw = (const float*)d_in[0];
  const float* w1  = (const float*)d_in[1];
  const float* b1  = (const float*)d_in[2];
  const float* w2  = (const float*)d_in[3];
  const float* b2  = (const float*)d_in[4];
  const float* w3  = (const float*)d_in[5];
  const float* b3  = (const float*)d_in[6];
  const int* pix_rc = (const int*)d_in[7];
  const int* seg    = (const int*)d_in[8];
  float* out = (float*)d_out;

  char* ws = (char*)d_ws;
  unsigned short* h2   = (unsigned short*)(ws + 33554432);   // [P][64] bf16, 33.55 MB
  unsigned short* feats = (unsigned short*)(ws + 67108864);  // [P][10] bf16, 5.25 MB
  unsigned short* wt2s = (unsigned short*)(ws + 72351744);   // 36864 shorts = 73728 B
  unsigned short* wt3s = (unsigned short*)(ws + 72425472);   // 9216 shorts = 18432 B
  unsigned short* zeros = (unsigned short*)(ws + 72443904);  // 256 B zero stub
  float* partials  = (float*)(ws + 0);                       // 512 * 11264 f32 = 23.07 MB
  float* partials2 = (float*)(ws + 23068672);                // 16 * 11264 f32 = 0.72 MB

  prep_k<<<180, 256, 0, stream>>>(w2, w3, wt2s, wt3s, zeros);
  conv2_k<<<2048, 256, 0, stream>>>(raw, w1, b1, wt2s, b2, h2);
  conv3_k<<<2048, 256, 0, stream>>>(h2, wt3s, b3, feats, zeros);
  scatter_k<<<SBLK, 256, 0, stream>>>(feats, pix_rc, seg, partials);
  finA_k<<<FGRP * 44, 256, 0, stream>>>(partials, partials2);
  finB_k<<<40, 256, 0, stream>>>(partials2, out);
}

// Round 10
// 83.664 us; speedup vs baseline: 2.4545x; 1.0114x over previous
//
#include <hip/hip_runtime.h>

typedef __attribute__((ext_vector_type(8))) short short8;
typedef __attribute__((ext_vector_type(4))) float f32x4;

constexpr int H = 512, W = 512;
constexpr int P = H * W;     // 262144
constexpr int NSP = 1024;
constexpr int SBLK = 512;    // scatter partial sets
constexpr int FGRP = 16;     // finalize stage-A groups (32 sets each)

__device__ inline unsigned short f2bf(float f) {
  unsigned u = __builtin_bit_cast(unsigned, f);
  unsigned r = (u + 0x7fffu + ((u >> 16) & 1u)) >> 16;  // RNE
  return (unsigned short)r;
}
__device__ inline float bflo(unsigned u) { return __builtin_bit_cast(float, u << 16); }
__device__ inline float bfhi(unsigned u) { return __builtin_bit_cast(float, u & 0xffff0000u); }

// XCD-band swizzle (bijective: grid % 8 == 0). cpx = grid/8. Producer and
// consumer kernels map XCD k to the same pixel-row band.
__device__ inline int xcd_swz(int b, int cpx) { return (b & 7) * cpx + (b >> 3); }

// ---------------- prep: weights -> staged-order bf16 with baked-in swizzle ----------------
__global__ __launch_bounds__(256) void prep_k(const float* __restrict__ w2,
                                              const float* __restrict__ w3,
                                              unsigned short* __restrict__ wt2s,
                                              unsigned short* __restrict__ wt3s,
                                              unsigned short* __restrict__ zeros) {
  if (blockIdx.x == 0 && threadIdx.x < 128) zeros[threadIdx.x] = 0;  // 256-B zero stub
  int i = blockIdx.x * 256 + threadIdx.x;
  if (i < 36864) {                     // conv2: 18 chunks x 2048 shorts (64 oc rows)
    int k = i >> 11;
    int t = (i >> 3) & 255;
    int e = i & 7;
    int r = t >> 2, sp = t & 3, s = sp ^ (r & 3);
    int tap = k >> 1, ic = (k & 1) * 32 + s * 8 + e;
    wt2s[i] = f2bf(w2[r * 576 + ic * 9 + tap]);
  } else if (i < 46080) {              // conv3: 18 chunks x 512 shorts (16 rows, 10 real)
    int j = i - 36864;
    int k = j >> 9;
    int t = (j >> 3) & 63;
    int e = j & 7;
    int r = t >> 2, sp = t & 3, s = sp ^ (r & 3);
    int tap = k >> 1, ic = (k & 1) * 32 + s * 8 + e;
    wt3s[j] = (r < 10) ? f2bf(w3[r * 576 + ic * 9 + tap]) : (unsigned short)0;
  }
}

// ---------------- conv2 (fused conv1-via-MFMA + conv2): raw -> h2 NHWC bf16; 32x8, 512 thr ----------------
__global__ __launch_bounds__(512) void conv2_k(const float* __restrict__ raw,
                                               const float* __restrict__ w1,
                                               const float* __restrict__ b1,
                                               const unsigned short* __restrict__ wts,
                                               const float* __restrict__ bias,
                                               unsigned short* __restrict__ ynhwc) {
  constexpr int WCS = 2048;                                // weight chunk shorts (4 KiB)
  __shared__ __align__(16) unsigned short acts[352 * 64];  // 45056 B
  __shared__ __align__(16) unsigned short wbuf[3 * WCS];   // 12288 B
  __shared__ float rawt[12 * 36];                          // 1728 B => 59072 B, 2 blk/CU
  int tid = threadIdx.x;
  int lane = tid & 63, wave = tid >> 6;                    // 8 waves
  int logical = xcd_swz(blockIdx.x, 128);
  int tilex = logical & 15, tiley = logical >> 4;
  int c0 = tilex * 32, r0 = tiley * 8;

  // ---- weight prologue chunks 0,1 (waves 0-3 only) ----
  if (tid < 256) {
#pragma unroll
    for (int k0 = 0; k0 < 2; ++k0) {
      const unsigned short* src = wts + (size_t)k0 * WCS + tid * 8;
      unsigned short* dstb = wbuf + k0 * WCS + wave * 512;
      __builtin_amdgcn_global_load_lds((const __attribute__((address_space(1))) void*)src,
                                       (__attribute__((address_space(3))) void*)dstb, 16, 0, 0);
    }
  }
  // ---- stage raw halo-of-halo [12 rows][36 cols] (rows r0-2 .. r0+9) ----
  if (tid < 432) {
    int rr = tid / 36, cc = tid - rr * 36;
    int gr = r0 + rr - 2, gc = c0 + cc - 2;
    bool ok = ((unsigned)gr < 512u) && ((unsigned)gc < 512u);
    rawt[tid] = ok ? raw[gr * 512 + gc] : 0.f;
  }

  int q = lane >> 4, n = lane & 15;
  int og1 = wave & 3;
  // A-frag for conv1: row = oc (og1*16+n), k = q*8+e; taps 0-8 real, rest 0.
  short8 a1f;
  {
    short av[8];
#pragma unroll
    for (int e = 0; e < 8; ++e) av[e] = 0;
    int oc = og1 * 16 + n;
    if (q == 0) {
#pragma unroll
      for (int e = 0; e < 8; ++e) av[e] = (short)f2bf(w1[oc * 9 + e]);
    } else if (q == 1) {
      av[0] = (short)f2bf(w1[oc * 9 + 8]);
    }
    a1f = (short8){av[0], av[1], av[2], av[3], av[4], av[5], av[6], av[7]};
  }
  float bb1[4];
#pragma unroll
  for (int r2 = 0; r2 < 4; ++r2) bb1[r2] = b1[og1 * 16 + q * 4 + r2];
  __syncthreads();  // rawt visible

  // ---- phase 1: conv1 via MFMA; waves 0-3: t=0..10, waves 4-7: t=11..21 ----
  char* actw = (char*)acts;
  int tbase = (wave < 4) ? 0 : 11;
  for (int ti = 0; ti < 11; ++ti) {
    int t = tbase + ti;
    int px = t * 16 + n;                                 // 0..351
    bool okp = px < 340;
    int prow = px / 34, pcol = px - prow * 34;
    int prc = okp ? prow : 9;                            // clamp rawt row for px>=340
    short bv[8];
#pragma unroll
    for (int e = 0; e < 8; ++e) bv[e] = 0;
    if (q == 0) {
#pragma unroll
      for (int e = 0; e < 8; ++e) {
        int dy = e / 3, dx = e - dy * 3;                 // taps 0..7
        bv[e] = (short)f2bf(rawt[(prc + dy) * 36 + pcol + dx]);
      }
    } else if (q == 1) {
      bv[0] = (short)f2bf(rawt[(prc + 2) * 36 + pcol + 2]);  // tap 8
    }
    short8 b1f = (short8){bv[0], bv[1], bv[2], bv[3], bv[4], bv[5], bv[6], bv[7]};
    f32x4 d = __builtin_amdgcn_mfma_f32_16x16x32_bf16(a1f, b1f,
                                                       (f32x4){0.f, 0.f, 0.f, 0.f}, 0, 0, 0);
    int gr1 = r0 + prow - 1, gc1 = c0 + pcol - 1;
    bool ok1 = okp && ((unsigned)gr1 < 512u) && ((unsigned)gc1 < 512u);
    float o0 = ok1 ? fmaxf(d.x + bb1[0], 0.f) : 0.f;
    float o1 = ok1 ? fmaxf(d.y + bb1[1], 0.f) : 0.f;
    float o2 = ok1 ? fmaxf(d.z + bb1[2], 0.f) : 0.f;
    float o3 = ok1 ? fmaxf(d.w + bb1[3], 0.f) : 0.f;
    unsigned lo = (unsigned)f2bf(o0) | ((unsigned)f2bf(o1) << 16);
    unsigned hi = (unsigned)f2bf(o2) | ((unsigned)f2bf(o3) << 16);
    int wa = px * 128 + ((((og1 * 2 + (q >> 1)) ^ (px & 7)) << 4)) + ((q & 1) << 3);
    *reinterpret_cast<uint2*>(actw + wa) = make_uint2(lo, hi);
  }
  __syncthreads();  // acts complete; full drain — ring bookkeeping starts clean

  // ---- phase 2: 18-step weight-ring k-loop; wave owns output row `wave` ----
  f32x4 acc[4][2];
#pragma unroll
  for (int og = 0; og < 4; ++og)
#pragma unroll
    for (int g = 0; g < 2; ++g) acc[og][g] = (f32x4){0.f, 0.f, 0.f, 0.f};

  int plbase[2];
#pragma unroll
  for (int g = 0; g < 2; ++g) plbase[g] = wave * 34 + 16 * g + n;
  const char* actb = (const char*)acts;

#pragma unroll
  for (int k = 0; k < 18; ++k) {
    if (k == 17) {
      asm volatile("s_waitcnt vmcnt(0)" ::: "memory");  // last chunk landed
    } else {
      asm volatile("s_waitcnt vmcnt(1)" ::: "memory");  // chunk k landed (in-order)
    }
    __builtin_amdgcn_sched_barrier(0);
    __builtin_amdgcn_s_barrier();                      // all parts landed; NO drain
    __builtin_amdgcn_sched_barrier(0);
    if (k + 2 < 18 && tid < 256) {                     // slot (k+2)%3 free: read at k-1
      const unsigned short* src = wts + (size_t)(k + 2) * WCS + tid * 8;
      unsigned short* dstb = wbuf + ((k + 2) % 3) * WCS + wave * 512;
      __builtin_amdgcn_global_load_lds((const __attribute__((address_space(1))) void*)src,
                                       (__attribute__((address_space(3))) void*)dstb, 16, 0, 0);
    }
    const int tap = k >> 1, kc = k & 1;
    const int kyy = tap / 3, kxx = tap - kyy * 3;
    const char* wb = (const char*)(wbuf + (k % 3) * WCS);
    short8 af[4];
#pragma unroll
    for (int og = 0; og < 4; ++og) {
      int r = og * 16 + n;
      af[og] = *reinterpret_cast<const short8*>(wb + r * 64 + ((q ^ (r & 3)) * 16));
    }
#pragma unroll
    for (int g = 0; g < 2; ++g) {
      int pl = plbase[g] + kyy * 34 + kxx;
      int addr = pl * 128 + (((kc * 4 + q) ^ (pl & 7)) * 16);
      short8 bf = *reinterpret_cast<const short8*>(actb + addr);
#pragma unroll
      for (int og = 0; og < 4; ++og)
        acc[og][g] = __builtin_amdgcn_mfma_f32_16x16x32_bf16(af[og], bf, acc[og][g], 0, 0, 0);
    }
  }

  // ---- epilogue: acc -> LDS (swizzled NHWC tile, 256 px) -> coalesced 16B stores ----
  __syncthreads();  // acts reads done; safe to reuse as output staging
  char* ob = (char*)acts;
#pragma unroll
  for (int og = 0; og < 4; ++og) {
    float b0 = bias[og * 16 + q * 4 + 0], b1v = bias[og * 16 + q * 4 + 1];
    float b2 = bias[og * 16 + q * 4 + 2], b3 = bias[og * 16 + q * 4 + 3];
#pragma unroll
    for (int g = 0; g < 2; ++g) {
      int pl = wave * 32 + g * 16 + n;
      f32x4 v = acc[og][g];
      float o0 = fmaxf(v.x + b0, 0.f), o1 = fmaxf(v.y + b1v, 0.f);
      float o2 = fmaxf(v.z + b2, 0.f), o3 = fmaxf(v.w + b3, 0.f);
      unsigned lo = (unsigned)f2bf(o0) | ((unsigned)f2bf(o1) << 16);
      unsigned hi = (unsigned)f2bf(o2) | ((unsigned)f2bf(o3) << 16);
      int lslot = og * 2 + (q >> 1);                   // logical 16B slot
      int wa = pl * 128 + (((lslot ^ (pl & 7)) << 4)) + ((q & 1) << 3);
      *reinterpret_cast<uint2*>(ob + wa) = make_uint2(lo, hi);
    }
  }
  __syncthreads();
  char* yb = (char*)ynhwc;
#pragma unroll
  for (int it = 0; it < 4; ++it) {
    int c = it * 512 + tid;                            // 2048 16-B chunks
    int pl = c >> 3, slot = c & 7;
    uint4 v = *reinterpret_cast<const uint4*>(ob + pl * 128 + ((slot ^ (pl & 7)) << 4));
    size_t gb = (((size_t)(r0 + (pl >> 5)) * 512) + c0 + (pl & 31)) * 128 + slot * 16;
    *reinterpret_cast<uint4*>(yb + gb) = v;
  }
}

// ---------------- conv3 (MFMA): 64 -> 10, NHWC bf16 out; 32x8 tile, 512 thr ----------------
__global__ __launch_bounds__(512) void conv3_k(const unsigned short* __restrict__ xin,
                                               const unsigned short* __restrict__ wts,
                                               const float* __restrict__ bias,
                                               unsigned short* __restrict__ feats,
                                               const unsigned short* __restrict__ zeros) {
  __shared__ __align__(16) unsigned short acts[352 * 64];  // 45056 B
  __shared__ __align__(16) unsigned short wl[9216];        // 18432 B => 63488 B, 2 blk/CU
  int tid = threadIdx.x;
  int lane = tid & 63, wave = tid >> 6;                    // 8 waves
  int logical = xcd_swz(blockIdx.x, 128);
  int tilex = logical & 15, tiley = logical >> 4;
  int c0 = tilex * 32, r0 = tiley * 8;

  // weights first (needed at k=0), then acts halo (344 used px, padded 352)
  for (int wi = wave; wi < 18; wi += 8) {
    const unsigned short* src = wts + (size_t)wi * 512 + lane * 8;
    unsigned short* dstb = &wl[wi * 512];
    __builtin_amdgcn_global_load_lds((const __attribute__((address_space(1))) void*)src,
                                     (__attribute__((address_space(3))) void*)dstb, 16, 0, 0);
  }
  for (int wi = wave; wi < 44; wi += 8) {
    int cidx = wi * 64 + lane;
    int pix = cidx >> 3, slotp = cidx & 7;
    int prow = pix / 34, pcol = pix - prow * 34;
    int gr = r0 + prow - 1, gc = c0 + pcol - 1;
    int slot = slotp ^ (pix & 7);
    bool ok = (pix < 340) & ((unsigned)gr < 512u) & ((unsigned)gc < 512u);
    const unsigned short* src = ok ? (xin + (((size_t)(gr * 512 + gc)) << 6) + slot * 8) : zeros;
    unsigned short* dstb = &acts[wi * 512];  // wave-uniform base
    __builtin_amdgcn_global_load_lds((const __attribute__((address_space(1))) void*)src,
                                     (__attribute__((address_space(3))) void*)dstb, 16, 0, 0);
  }
  __syncthreads();

  int q = lane >> 4, n = lane & 15;
  f32x4 acc[2];
#pragma unroll
  for (int g = 0; g < 2; ++g) acc[g] = (f32x4){0.f, 0.f, 0.f, 0.f};
  int plbase[2];
#pragma unroll
  for (int g = 0; g < 2; ++g) plbase[g] = wave * 34 + 16 * g + n;
  const char* actb = (const char*)acts;
  const char* wb0 = (const char*)wl;

#pragma unroll
  for (int k = 0; k < 18; ++k) {                           // no barriers, no waitcnts
    const int tap = k >> 1, kc = k & 1;
    const int kyy = tap / 3, kxx = tap - kyy * 3;
    short8 af = *reinterpret_cast<const short8*>(wb0 + k * 1024 + n * 64 + ((q ^ (n & 3)) * 16));
#pragma unroll
    for (int g = 0; g < 2; ++g) {
      int pl = plbase[g] + kyy * 34 + kxx;
      int addr = pl * 128 + (((kc * 4 + q) ^ (pl & 7)) * 16);
      short8 bf = *reinterpret_cast<const short8*>(actb + addr);
      acc[g] = __builtin_amdgcn_mfma_f32_16x16x32_bf16(af, bf, acc[g], 0, 0, 0);
    }
  }

  // ---- epilogue: acc -> bf16 in LDS (24B/px rows) -> coalesced 4B copies ----
  __syncthreads();
  char* ob = (char*)acts;
  float bb[4];
#pragma unroll
  for (int r2 = 0; r2 < 4; ++r2) {
    int oc = q * 4 + r2;
    bb[r2] = (oc < 10) ? bias[oc] : 0.f;
  }
#pragma unroll
  for (int g = 0; g < 2; ++g) {
    int pl = wave * 32 + g * 16 + n;
    f32x4 v = acc[g];
    float o0 = v.x + bb[0], o1 = v.y + bb[1], o2 = v.z + bb[2], o3 = v.w + bb[3];
    if (q < 2) {
      unsigned u0 = (unsigned)f2bf(o0) | ((unsigned)f2bf(o1) << 16);
      unsigned u1 = (unsigned)f2bf(o2) | ((unsigned)f2bf(o3) << 16);
      *reinterpret_cast<uint2*>(ob + pl * 24 + q * 8) = make_uint2(u0, u1);
    } else if (q == 2) {
      *reinterpret_cast<unsigned*>(ob + pl * 24 + 16) =
          (unsigned)f2bf(o0) | ((unsigned)f2bf(o1) << 16);
    }
  }
  __syncthreads();
  char* fb = (char*)feats;
#pragma unroll
  for (int it = 0; it < 3; ++it) {
    int c = it * 512 + tid;                            // 1280 4-B words (8 rows x 640 B)
    if (c < 1280) {
      int row = c / 160, wb = c - row * 160;
      int byte = wb * 4;
      int px = byte / 20, off = byte - px * 20;
      unsigned v = *reinterpret_cast<const unsigned*>(ob + (row * 32 + px) * 24 + off);
      size_t gbyte = (((size_t)(r0 + row) * 512) + c0) * 20 + (size_t)byte;
      *reinterpret_cast<unsigned*>(fb + gbyte) = v;
    }
  }
}

// ---------------- scatter: LDS accumulate -> per-block partials (bf16 feats); 512 thr ----------------
__global__ __launch_bounds__(512) void scatter_k(const unsigned short* __restrict__ feats,  // [P][10] bf16
                                                 const int* __restrict__ pix_rc,
                                                 const int* __restrict__ seg,
                                                 float* __restrict__ partials) {
  __shared__ float ls[NSP * 10];
  __shared__ float lc[NSP];
  int tid = threadIdx.x;
  for (int i = tid; i < NSP * 10; i += 512) ls[i] = 0.f;
  for (int i = tid; i < NSP; i += 512) lc[i] = 0.f;
  __syncthreads();

  constexpr int PER = P / SBLK;  // 512
  int p0 = blockIdx.x * PER;
  for (int p = p0 + tid; p < p0 + PER; p += 512) {
    int r = pix_rc[2 * p], c = pix_rc[2 * p + 1];
    int s = seg[p];
    size_t gpix = (size_t)r * 512 + c;
    const char* fp = (const char*)feats + gpix * 20;
    uint4 a = *reinterpret_cast<const uint4*>(fp);       // 16 B (4-aligned)
    unsigned e = *reinterpret_cast<const unsigned*>(fp + 16);
    float v[10];
    v[0] = bflo(a.x); v[1] = bfhi(a.x);
    v[2] = bflo(a.y); v[3] = bfhi(a.y);
    v[4] = bflo(a.z); v[5] = bfhi(a.z);
    v[6] = bflo(a.w); v[7] = bfhi(a.w);
    v[8] = bflo(e);   v[9] = bfhi(e);
#pragma unroll
    for (int ch = 0; ch < 10; ++ch) atomicAdd(&ls[s * 10 + ch], v[ch]);
    atomicAdd(&lc[s], 1.f);
  }
  __syncthreads();

  float* outp = partials + (size_t)blockIdx.x * (NSP * 11);
  for (int i = tid; i < NSP * 10; i += 512) outp[i] = ls[i];
  for (int i = tid; i < NSP; i += 512) outp[NSP * 10 + i] = lc[i];
}

// ---------------- finalize stage A: 16 groups x 32 sets -> partials2 ----------------
__global__ __launch_bounds__(256) void finA_k(const float* __restrict__ partials,
                                              float* __restrict__ partials2) {
  int g = blockIdx.x / 44;                        // 44 blocks/group (44*256 = 11264)
  int e = (blockIdx.x - g * 44) * 256 + threadIdx.x;
  const float* base = partials + (size_t)(g * 32) * (NSP * 11) + e;
  float s = 0.f;
#pragma unroll 8
  for (int k = 0; k < 32; ++k) s += base[(size_t)k * (NSP * 11)];
  partials2[(size_t)g * (NSP * 11) + e] = s;
}

// ---------------- finalize stage B: sum 16 groups, divide ----------------
__global__ __launch_bounds__(256) void finB_k(const float* __restrict__ partials2,
                                              float* __restrict__ out) {
  int i = blockIdx.x * 256 + threadIdx.x;
  if (i >= NSP * 10) return;
  int sp = i / 10;
  float s = 0.f, cnt = 0.f;
#pragma unroll
  for (int g = 0; g < FGRP; ++g) {
    const float* pp = partials2 + (size_t)g * (NSP * 11);
    s += pp[i];
    cnt += pp[NSP * 10 + sp];
  }
  out[i] = s / fmaxf(cnt, 1.f);
}

extern "C" void kernel_launch(void* const* d_in, const int* in_sizes, int n_in,
                              void* d_out, int out_size, void* d_ws, size_t ws_size,
                              hipStream_t stream) {
  const float* raw = (const float*)d_in[0];
  const float* w1  = (const float*)d_in[1];
  const float* b1  = (const float*)d_in[2];
  const float* w2  = (const float*)d_in[3];
  const float* b2  = (const float*)d_in[4];
  const float* w3  = (const float*)d_in[5];
  const float* b3  = (const float*)d_in[6];
  const int* pix_rc = (const int*)d_in[7];
  const int* seg    = (const int*)d_in[8];
  float* out = (float*)d_out;

  char* ws = (char*)d_ws;
  unsigned short* h2   = (unsigned short*)(ws + 33554432);   // [P][64] bf16, 33.55 MB
  unsigned short* feats = (unsigned short*)(ws + 67108864);  // [P][10] bf16, 5.25 MB
  unsigned short* wt2s = (unsigned short*)(ws + 72351744);   // 36864 shorts = 73728 B
  unsigned short* wt3s = (unsigned short*)(ws + 72425472);   // 9216 shorts = 18432 B
  unsigned short* zeros = (unsigned short*)(ws + 72443904);  // 256 B zero stub
  float* partials  = (float*)(ws + 0);                       // 512 * 11264 f32 = 23.07 MB
  float* partials2 = (float*)(ws + 23068672);                // 16 * 11264 f32 = 0.72 MB

  prep_k<<<180, 256, 0, stream>>>(w2, w3, wt2s, wt3s, zeros);
  conv2_k<<<1024, 512, 0, stream>>>(raw, w1, b1, wt2s, b2, h2);
  conv3_k<<<1024, 512, 0, stream>>>(h2, wt3s, b3, feats, zeros);
  scatter_k<<<SBLK, 512, 0, stream>>>(feats, pix_rc, seg, partials);
  finA_k<<<FGRP * 44, 256, 0, stream>>>(partials, partials2);
  finB_k<<<40, 256, 0, stream>>>(partials2, out);
}